// Round 1
// baseline (682.772 us; speedup 1.0000x reference)
//
#include <hip/hip_runtime.h>
#include <cstddef>

constexpr int Bn = 16, Kn = 256, Rn = 256, Tn = 1000, C8 = 8, SW = 16;
constexpr size_t UP_SZ   = (size_t)Bn * Tn * Rn;          // 4,096,000
constexpr size_t MASK_OFF = UP_SZ;                         // + 16,000
constexpr size_t LEN_OFF  = MASK_OFF + (size_t)Bn * Tn;    // + 16
constexpr size_t W_OFF    = LEN_OFF + Bn;                  // + 4,096,000

__device__ __forceinline__ float silu_f(float x) { return x / (1.f + __expf(-x)); }

// ---------------- Kernel A: per-batch scan, length, mask ----------------
__global__ __launch_bounds__(256) void scan_kernel(
    const float* __restrict__ dur,
    float* __restrict__ s_k, float* __restrict__ e_k, int* __restrict__ len_ws,
    float* __restrict__ out)
{
    const int b = blockIdx.x, tid = threadIdx.x;
    __shared__ float sc[Kn];
    const float d = dur[b * Kn + tid];
    sc[tid] = d;
    __syncthreads();
    for (int off = 1; off < Kn; off <<= 1) {
        float v = (tid >= off) ? sc[tid - off] : 0.f;
        __syncthreads();
        sc[tid] += v;
        __syncthreads();
    }
    const float e = sc[tid];
    e_k[b * Kn + tid] = e;
    s_k[b * Kn + tid] = e - d;
    const float total = sc[Kn - 1];
    int len = (int)rintf(total);
    if (len > Tn) len = Tn;
    if (tid == 0) { len_ws[b] = len; out[LEN_OFF + b] = (float)len; }
    for (int t = tid; t < Tn; t += 256)
        out[MASK_OFF + (size_t)b * Tn + t] = (t >= len) ? 1.f : 0.f;
}

// ---------------- Kernel B: conv blocks + base precompute ----------------
__device__ __forceinline__ void conv_post(
    const float* acc, const float* cb, const float* bng, const float* bnb,
    const float* lng, const float* lnb, const float* w1, const float* b1,
    float* __restrict__ dst)
{
    const float bnscale = rsqrtf(1.f + 1e-5f);
    float x[C8];
    float mu = 0.f;
#pragma unroll
    for (int c = 0; c < C8; c++) {
        float v = (acc[c] + cb[c]) * (bng[c] * bnscale) + bnb[c];
        v = silu_f(v);
        x[c] = v; mu += v;
    }
    mu *= (1.f / C8);
    float var = 0.f;
#pragma unroll
    for (int c = 0; c < C8; c++) { float dd = x[c] - mu; var += dd * dd; }
    var *= (1.f / C8);
    const float rs = rsqrtf(var + 1e-5f);
    float y[C8];
#pragma unroll
    for (int c = 0; c < C8; c++) y[c] = (x[c] - mu) * rs * lng[c] + lnb[c];
#pragma unroll
    for (int c2 = 0; c2 < SW; c2++) {
        float a = b1[c2];
#pragma unroll
        for (int p = 0; p < C8; p++) a += y[p] * w1[(2 + p) * SW + c2];
        dst[c2] = a;
    }
}

__global__ __launch_bounds__(256) void conv_kernel(
    const float* __restrict__ V,
    const float* __restrict__ wW, const float* __restrict__ bW,
    const float* __restrict__ bngW, const float* __restrict__ bnbW,
    const float* __restrict__ lngW, const float* __restrict__ lnbW,
    const float* __restrict__ wC, const float* __restrict__ bC,
    const float* __restrict__ bngC, const float* __restrict__ bnbC,
    const float* __restrict__ lngC, const float* __restrict__ lnbC,
    const float* __restrict__ sww_w1, const float* __restrict__ sww_b1,
    const float* __restrict__ swc_w1, const float* __restrict__ swc_b1,
    float* __restrict__ base_w, float* __restrict__ base_c)
{
    const int b = blockIdx.x, tid = threadIdx.x;
    constexpr int RT = 32, PAD = 33;
    __shared__ float vt[Kn * PAD];
    float aw[C8], ac[C8];
#pragma unroll
    for (int c = 0; c < C8; c++) { aw[c] = 0.f; ac[c] = 0.f; }

    for (int r0 = 0; r0 < Rn; r0 += RT) {
        __syncthreads();
        for (int i = tid; i < Kn * RT; i += 256) {
            const int row = i >> 5, r = i & 31;
            vt[row * PAD + r] = V[((size_t)b * Kn + row) * Rn + r0 + r];
        }
        __syncthreads();
        for (int dk = 0; dk < 3; dk++) {
            const int row = tid + dk - 1;
            const bool valid = (row >= 0) && (row < Kn);
            const float* wp = wW + (size_t)(dk * Rn + r0) * C8;
            const float* cp = wC + (size_t)(dk * Rn + r0) * C8;
            for (int r = 0; r < RT; r++) {
                const float v = valid ? vt[row * PAD + r] : 0.f;
#pragma unroll
                for (int c = 0; c < C8; c++) {
                    aw[c] += v * wp[r * C8 + c];
                    ac[c] += v * cp[r * C8 + c];
                }
            }
        }
    }
    conv_post(aw, bW, bngW, bnbW, lngW, lnbW, sww_w1, sww_b1,
              base_w + ((size_t)b * Kn + tid) * SW);
    conv_post(ac, bC, bngC, bnbC, lngC, lnbC, swc_w1, swc_b1,
              base_c + ((size_t)b * Kn + tid) * SW);
}

// ---------------- Kernel C: main per-(b,t) kernel ----------------
__global__ __launch_bounds__(256) void main_kernel(
    const float* __restrict__ V, const unsigned char* __restrict__ text_mask,
    const float* __restrict__ s_k, const float* __restrict__ e_k,
    const int* __restrict__ len_ws,
    const float* __restrict__ base_w, const float* __restrict__ base_c,
    const float* __restrict__ sww_w1, const float* __restrict__ sww_w2, const float* __restrict__ sww_b2,
    const float* __restrict__ proj_w, const float* __restrict__ proj_b,
    const float* __restrict__ swc_w1, const float* __restrict__ swc_w2, const float* __restrict__ swc_b2,
    const float* __restrict__ lin_e_w, const float* __restrict__ lin_e_b,
    const float* __restrict__ ln_o_g, const float* __restrict__ ln_o_b,
    float* __restrict__ out)
{
    const int t = blockIdx.x, b = blockIdx.y, tid = threadIdx.x;
    float* __restrict__ up_out = out + ((size_t)b * Tn + t) * Rn;
    float* __restrict__ W_out  = out + W_OFF + ((size_t)b * Tn + t) * Kn;
    const int len = len_ws[b];
    if (t >= len) { up_out[tid] = 0.f; W_out[tid] = 0.f; return; }

    __shared__ float W_lds[Kn];
    __shared__ float red[4];
    __shared__ float aggs[4 * SW];
    __shared__ float agg_lds[SW];

    const int lane = tid & 63, wid = tid >> 6;
    const bool tmask = text_mask[b * Kn + tid] != 0;
    const float tv = (float)(t + 1);
    const float skv = s_k[b * Kn + tid], ekv = e_k[b * Kn + tid];
    const float Sv = tmask ? 0.f : tv - skv;
    const float Ev = tmask ? 0.f : ekv - tv;

    // ---- W swish block -> logit ----
    float logit;
    {
        const float* bse = base_w + ((size_t)b * Kn + tid) * SW;
        float h[SW];
#pragma unroll
        for (int c = 0; c < SW; c++)
            h[c] = silu_f(Sv * sww_w1[c] + Ev * sww_w1[SW + c] + bse[c]);
        float acc = proj_b[0];
#pragma unroll
        for (int c2 = 0; c2 < SW; c2++) {
            float o = sww_b2[c2];
#pragma unroll
            for (int c = 0; c < SW; c++) o += h[c] * sww_w2[c * SW + c2];
            acc += silu_f(o) * proj_w[c2];
        }
        logit = tmask ? -INFINITY : acc;
    }

    // ---- softmax over K ----
    float m = logit;
#pragma unroll
    for (int off = 32; off >= 1; off >>= 1) m = fmaxf(m, __shfl_xor(m, off, 64));
    if (lane == 0) red[wid] = m;
    __syncthreads();
    m = fmaxf(fmaxf(red[0], red[1]), fmaxf(red[2], red[3]));
    __syncthreads();
    const float pex = __expf(logit - m);
    float ssum = pex;
#pragma unroll
    for (int off = 32; off >= 1; off >>= 1) ssum += __shfl_xor(ssum, off, 64);
    if (lane == 0) red[wid] = ssum;
    __syncthreads();
    ssum = red[0] + red[1] + red[2] + red[3];
    const float wgt = pex / ssum;
    W_lds[tid] = wgt;
    W_out[tid] = wgt;

    // ---- C swish block ----
    float oc[SW];
    {
        const float* bse = base_c + ((size_t)b * Kn + tid) * SW;
        float h[SW];
#pragma unroll
        for (int c = 0; c < SW; c++)
            h[c] = silu_f(Sv * swc_w1[c] + Ev * swc_w1[SW + c] + bse[c]);
#pragma unroll
        for (int c2 = 0; c2 < SW; c2++) {
            float o = swc_b2[c2];
#pragma unroll
            for (int c = 0; c < SW; c++) o += h[c] * swc_w2[c * SW + c2];
            oc[c2] = silu_f(o);
        }
    }

    // ---- agg[p] = sum_k wgt*oc[p] ----
    __syncthreads();   // red free; W_lds now visible to all
#pragma unroll
    for (int pch = 0; pch < SW; pch++) {
        float v = wgt * oc[pch];
#pragma unroll
        for (int off = 32; off >= 1; off >>= 1) v += __shfl_xor(v, off, 64);
        if (lane == 0) aggs[wid * SW + pch] = v;
    }
    __syncthreads();
    if (tid < SW)
        agg_lds[tid] = aggs[tid] + aggs[SW + tid] + aggs[2 * SW + tid] + aggs[3 * SW + tid];
    __syncthreads();

    // ---- up[r] = (W@V)[r] + (agg@lin_e)[r] + lin_e_b[r], then LN ----
    const int r = tid;
    float acc = lin_e_b[r];
#pragma unroll
    for (int pch = 0; pch < SW; pch++) acc += agg_lds[pch] * lin_e_w[pch * Rn + r];
    const float* Vb = V + (size_t)b * Kn * Rn + r;
#pragma unroll 8
    for (int k4 = 0; k4 < Kn / 4; k4++) {
        const float4 wv = *(const float4*)&W_lds[k4 * 4];
        const float* vp = Vb + (size_t)(k4 * 4) * Rn;
        acc += wv.x * vp[0] + wv.y * vp[Rn] + wv.z * vp[2 * Rn] + wv.w * vp[3 * Rn];
    }
    float su = acc;
#pragma unroll
    for (int off = 32; off >= 1; off >>= 1) su += __shfl_xor(su, off, 64);
    if (lane == 0) red[wid] = su;
    __syncthreads();
    su = red[0] + red[1] + red[2] + red[3];
    __syncthreads();
    const float mu = su * (1.f / Rn);
    const float dv = acc - mu;
    float vr = dv * dv;
#pragma unroll
    for (int off = 32; off >= 1; off >>= 1) vr += __shfl_xor(vr, off, 64);
    if (lane == 0) red[wid] = vr;
    __syncthreads();
    vr = (red[0] + red[1] + red[2] + red[3]) * (1.f / Rn);
    up_out[r] = dv * rsqrtf(vr + 1e-5f) * ln_o_g[r] + ln_o_b[r];
}

// ---------------- launch ----------------
extern "C" void kernel_launch(void* const* d_in, const int* in_sizes, int n_in,
                              void* d_out, int out_size, void* d_ws, size_t ws_size,
                              hipStream_t stream)
{
    const float* dur       = (const float*)d_in[0];
    const float* V         = (const float*)d_in[1];
    // d_in[2] = pos_text (unused by reference)
    const unsigned char* text_mask = (const unsigned char*)d_in[3];
    const float* conv_c_w  = (const float*)d_in[4];
    const float* conv_c_b  = (const float*)d_in[5];
    const float* bn_c_g    = (const float*)d_in[6];
    const float* bn_c_b    = (const float*)d_in[7];
    const float* ln_c_g    = (const float*)d_in[8];
    const float* ln_c_b    = (const float*)d_in[9];
    const float* conv_w_w  = (const float*)d_in[10];
    const float* conv_w_b  = (const float*)d_in[11];
    const float* bn_w_g    = (const float*)d_in[12];
    const float* bn_w_b    = (const float*)d_in[13];
    const float* ln_w_g    = (const float*)d_in[14];
    const float* ln_w_b    = (const float*)d_in[15];
    const float* swc_w1    = (const float*)d_in[16];
    const float* swc_b1    = (const float*)d_in[17];
    const float* swc_w2    = (const float*)d_in[18];
    const float* swc_b2    = (const float*)d_in[19];
    const float* sww_w1    = (const float*)d_in[20];
    const float* sww_b1    = (const float*)d_in[21];
    const float* sww_w2    = (const float*)d_in[22];
    const float* sww_b2    = (const float*)d_in[23];
    const float* proj_w_w  = (const float*)d_in[24];
    const float* proj_w_b  = (const float*)d_in[25];
    const float* lin_e_w   = (const float*)d_in[26];
    const float* lin_e_b   = (const float*)d_in[27];
    const float* ln_o_g    = (const float*)d_in[28];
    const float* ln_o_b    = (const float*)d_in[29];

    float* out = (float*)d_out;
    float* wsf = (float*)d_ws;
    float* s_k    = wsf;                 // 4096
    float* e_k    = wsf + 4096;          // 4096
    float* base_w = wsf + 8192;          // 65536
    float* base_c = base_w + 65536;      // 65536
    int*   len_ws = (int*)(base_c + 65536); // 16

    scan_kernel<<<dim3(Bn), dim3(Kn), 0, stream>>>(dur, s_k, e_k, len_ws, out);
    conv_kernel<<<dim3(Bn), dim3(256), 0, stream>>>(
        V,
        conv_w_w, conv_w_b, bn_w_g, bn_w_b, ln_w_g, ln_w_b,
        conv_c_w, conv_c_b, bn_c_g, bn_c_b, ln_c_g, ln_c_b,
        sww_w1, sww_b1, swc_w1, swc_b1,
        base_w, base_c);
    main_kernel<<<dim3(Tn, Bn), dim3(256), 0, stream>>>(
        V, text_mask, s_k, e_k, len_ws, base_w, base_c,
        sww_w1, sww_w2, sww_b2, proj_w_w, proj_w_b,
        swc_w1, swc_w2, swc_b2,
        lin_e_w, lin_e_b, ln_o_g, ln_o_b, out);
}

// Round 2
// 267.317 us; speedup vs baseline: 2.5542x; 2.5542x over previous
//
#include <hip/hip_runtime.h>
#include <cstddef>

constexpr int Bn = 16, Kn = 256, Rn = 256, Tn = 1000, C8 = 8, SW = 16;
constexpr size_t UP_SZ    = (size_t)Bn * Tn * Rn;          // 4,096,000
constexpr size_t MASK_OFF = UP_SZ;                          // + 16,000
constexpr size_t LEN_OFF  = MASK_OFF + (size_t)Bn * Tn;     // + 16
constexpr size_t W_OFF    = LEN_OFF + Bn;                    // + 4,096,000

__device__ __forceinline__ float fast_rcp(float x) { return __builtin_amdgcn_rcpf(x); }
__device__ __forceinline__ float fast_exp2(float x) { return __builtin_amdgcn_exp2f(x); }
constexpr float LOG2E = 1.44269504088896340736f;
__device__ __forceinline__ float silu_f(float x) {
    return x * fast_rcp(1.f + fast_exp2(-LOG2E * x));
}

// ---------------- Kernel A: per-batch scan, length, mask ----------------
__global__ __launch_bounds__(256) void scan_kernel(
    const float* __restrict__ dur,
    float* __restrict__ s_k, float* __restrict__ e_k, int* __restrict__ len_ws,
    float* __restrict__ out)
{
    const int b = blockIdx.x, tid = threadIdx.x;
    __shared__ float sc[Kn];
    const float d = dur[b * Kn + tid];
    sc[tid] = d;
    __syncthreads();
    for (int off = 1; off < Kn; off <<= 1) {
        float v = (tid >= off) ? sc[tid - off] : 0.f;
        __syncthreads();
        sc[tid] += v;
        __syncthreads();
    }
    const float e = sc[tid];
    e_k[b * Kn + tid] = e;
    s_k[b * Kn + tid] = e - d;
    const float total = sc[Kn - 1];
    int len = (int)rintf(total);
    if (len > Tn) len = Tn;
    if (tid == 0) { len_ws[b] = len; out[LEN_OFF + b] = (float)len; }
    for (int t = tid; t < Tn; t += 256)
        out[MASK_OFF + (size_t)b * Tn + t] = (t >= len) ? 1.f : 0.f;
}

// ---------------- conv phase A: partial sums over r-chunks ----------------
__global__ __launch_bounds__(256) void conv_partial_kernel(
    const float* __restrict__ V,
    const float* __restrict__ wW, const float* __restrict__ wC,
    float* __restrict__ part)
{
    const int rc = blockIdx.x, b = blockIdx.y, k = threadIdx.x;
    constexpr int RPAD = 33;
    __shared__ float vt[258 * RPAD];
    if (k < 16) {
        const int row = (k < 8) ? 0 : 257;
        const int j = (k & 7) * 4;
        vt[row * RPAD + j] = 0.f; vt[row * RPAD + j + 1] = 0.f;
        vt[row * RPAD + j + 2] = 0.f; vt[row * RPAD + j + 3] = 0.f;
    }
    const float* vsrc = V + ((size_t)(b * Kn + k)) * Rn + rc * 32;
#pragma unroll
    for (int j = 0; j < 8; j++) {
        const float4 q = *(const float4*)(vsrc + j * 4);
        float* dst = &vt[(k + 1) * RPAD + j * 4];
        dst[0] = q.x; dst[1] = q.y; dst[2] = q.z; dst[3] = q.w;
    }
    __syncthreads();

    float aw[C8], ac[C8];
#pragma unroll
    for (int c = 0; c < C8; c++) { aw[c] = 0.f; ac[c] = 0.f; }
    for (int dk = 0; dk < 3; dk++) {
        const float* wp = wW + (size_t)(dk * Rn + rc * 32) * C8;
        const float* cp = wC + (size_t)(dk * Rn + rc * 32) * C8;
        const float* vrow = &vt[(k + dk) * RPAD];
#pragma unroll 4
        for (int r = 0; r < 32; r++) {
            const float v = vrow[r];
#pragma unroll
            for (int c = 0; c < C8; c++) {
                aw[c] = fmaf(v, wp[r * C8 + c], aw[c]);
                ac[c] = fmaf(v, cp[r * C8 + c], ac[c]);
            }
        }
    }
    float* dst = part + ((size_t)(b * 8 + rc) * Kn + k) * 16;
    *(float4*)(dst + 0)  = make_float4(aw[0], aw[1], aw[2], aw[3]);
    *(float4*)(dst + 4)  = make_float4(aw[4], aw[5], aw[6], aw[7]);
    *(float4*)(dst + 8)  = make_float4(ac[0], ac[1], ac[2], ac[3]);
    *(float4*)(dst + 12) = make_float4(ac[4], ac[5], ac[6], ac[7]);
}

// ---------------- conv phase B: reduce partials + post + base ----------------
__device__ __forceinline__ void conv_post(
    const float* acc, const float* cb, const float* bng, const float* bnb,
    const float* lng, const float* lnb, const float* w1, const float* b1,
    float* __restrict__ dst)
{
    const float bnscale = rsqrtf(1.f + 1e-5f);
    float x[C8];
    float mu = 0.f;
#pragma unroll
    for (int c = 0; c < C8; c++) {
        float v = (acc[c] + cb[c]) * (bng[c] * bnscale) + bnb[c];
        v = silu_f(v);
        x[c] = v; mu += v;
    }
    mu *= (1.f / C8);
    float var = 0.f;
#pragma unroll
    for (int c = 0; c < C8; c++) { float dd = x[c] - mu; var += dd * dd; }
    var *= (1.f / C8);
    const float rs = rsqrtf(var + 1e-5f);
    float y[C8];
#pragma unroll
    for (int c = 0; c < C8; c++) y[c] = (x[c] - mu) * rs * lng[c] + lnb[c];
#pragma unroll
    for (int c2 = 0; c2 < SW; c2++) {
        float a = b1[c2];
#pragma unroll
        for (int p = 0; p < C8; p++) a = fmaf(y[p], w1[(2 + p) * SW + c2], a);
        dst[c2] = a;
    }
}

__global__ __launch_bounds__(256) void conv_finish_kernel(
    const float* __restrict__ part,
    const float* __restrict__ bW, const float* __restrict__ bngW, const float* __restrict__ bnbW,
    const float* __restrict__ lngW, const float* __restrict__ lnbW,
    const float* __restrict__ bC, const float* __restrict__ bngC, const float* __restrict__ bnbC,
    const float* __restrict__ lngC, const float* __restrict__ lnbC,
    const float* __restrict__ sww_w1, const float* __restrict__ sww_b1,
    const float* __restrict__ swc_w1, const float* __restrict__ swc_b1,
    float* __restrict__ base_w, float* __restrict__ base_c)
{
    const int b = blockIdx.x, k = threadIdx.x;
    float aw[C8], ac[C8];
#pragma unroll
    for (int c = 0; c < C8; c++) { aw[c] = 0.f; ac[c] = 0.f; }
#pragma unroll 2
    for (int rc = 0; rc < 8; rc++) {
        const float4* p = (const float4*)(part + ((size_t)(b * 8 + rc) * Kn + k) * 16);
        const float4 q0 = p[0], q1 = p[1], q2 = p[2], q3 = p[3];
        aw[0] += q0.x; aw[1] += q0.y; aw[2] += q0.z; aw[3] += q0.w;
        aw[4] += q1.x; aw[5] += q1.y; aw[6] += q1.z; aw[7] += q1.w;
        ac[0] += q2.x; ac[1] += q2.y; ac[2] += q2.z; ac[3] += q2.w;
        ac[4] += q3.x; ac[5] += q3.y; ac[6] += q3.z; ac[7] += q3.w;
    }
    conv_post(aw, bW, bngW, bnbW, lngW, lnbW, sww_w1, sww_b1,
              base_w + ((size_t)(b * Kn) + k) * SW);
    conv_post(ac, bC, bngC, bnbC, lngC, lnbC, swc_w1, swc_b1,
              base_c + ((size_t)(b * Kn) + k) * SW);
}

// ---------------- C1: swish blocks + softmax + W + agg ----------------
__global__ __launch_bounds__(256) void logits_kernel(
    const unsigned char* __restrict__ text_mask,
    const float* __restrict__ s_k, const float* __restrict__ e_k,
    const int* __restrict__ len_ws,
    const float* __restrict__ base_w, const float* __restrict__ base_c,
    const float* __restrict__ sww_w1, const float* __restrict__ sww_w2, const float* __restrict__ sww_b2,
    const float* __restrict__ proj_w, const float* __restrict__ proj_b,
    const float* __restrict__ swc_w1, const float* __restrict__ swc_w2, const float* __restrict__ swc_b2,
    float* __restrict__ agg_ws,
    float* __restrict__ out)
{
    const int t = blockIdx.x, b = blockIdx.y, tid = threadIdx.x;
    float* __restrict__ W_out = out + W_OFF + ((size_t)b * Tn + t) * Kn;
    const int len = len_ws[b];
    if (t >= len) { W_out[tid] = 0.f; return; }

    __shared__ float trn[Kn * 17];
    __shared__ float red[4];
    __shared__ float aggp[4][16];

    const int lane = tid & 63, wid = tid >> 6;
    const bool tmask = text_mask[b * Kn + tid] != 0;
    const float tv = (float)(t + 1);
    const float skv = s_k[b * Kn + tid], ekv = e_k[b * Kn + tid];
    const float Sv = tmask ? 0.f : tv - skv;
    const float Ev = tmask ? 0.f : ekv - tv;

    // ---- W swish block -> logit ----
    float logit;
    {
        float bw[SW];
        const float4* bp = (const float4*)(base_w + ((size_t)(b * Kn) + tid) * SW);
        { float4 q0 = bp[0], q1 = bp[1], q2 = bp[2], q3 = bp[3];
          bw[0]=q0.x; bw[1]=q0.y; bw[2]=q0.z; bw[3]=q0.w;
          bw[4]=q1.x; bw[5]=q1.y; bw[6]=q1.z; bw[7]=q1.w;
          bw[8]=q2.x; bw[9]=q2.y; bw[10]=q2.z; bw[11]=q2.w;
          bw[12]=q3.x; bw[13]=q3.y; bw[14]=q3.z; bw[15]=q3.w; }
        float h[SW];
#pragma unroll
        for (int c = 0; c < SW; c++)
            h[c] = silu_f(fmaf(Sv, sww_w1[c], fmaf(Ev, sww_w1[SW + c], bw[c])));
        float acc = proj_b[0];
#pragma unroll
        for (int c2 = 0; c2 < SW; c2++) {
            float o = sww_b2[c2];
#pragma unroll
            for (int c = 0; c < SW; c++) o = fmaf(h[c], sww_w2[c * SW + c2], o);
            acc = fmaf(silu_f(o), proj_w[c2], acc);
        }
        logit = tmask ? -INFINITY : acc;
    }

    // ---- softmax over K ----
    float m = logit;
#pragma unroll
    for (int off = 32; off >= 1; off >>= 1) m = fmaxf(m, __shfl_xor(m, off, 64));
    if (lane == 0) red[wid] = m;
    __syncthreads();
    m = fmaxf(fmaxf(red[0], red[1]), fmaxf(red[2], red[3]));
    __syncthreads();
    const float pex = fast_exp2(LOG2E * (logit - m));
    float ssum = pex;
#pragma unroll
    for (int off = 32; off >= 1; off >>= 1) ssum += __shfl_xor(ssum, off, 64);
    if (lane == 0) red[wid] = ssum;
    __syncthreads();
    ssum = red[0] + red[1] + red[2] + red[3];
    const float wgt = pex * fast_rcp(ssum);
    W_out[tid] = wgt;

    // ---- C swish block ----
    float oc[SW];
    {
        float bc[SW];
        const float4* bp = (const float4*)(base_c + ((size_t)(b * Kn) + tid) * SW);
        { float4 q0 = bp[0], q1 = bp[1], q2 = bp[2], q3 = bp[3];
          bc[0]=q0.x; bc[1]=q0.y; bc[2]=q0.z; bc[3]=q0.w;
          bc[4]=q1.x; bc[5]=q1.y; bc[6]=q1.z; bc[7]=q1.w;
          bc[8]=q2.x; bc[9]=q2.y; bc[10]=q2.z; bc[11]=q2.w;
          bc[12]=q3.x; bc[13]=q3.y; bc[14]=q3.z; bc[15]=q3.w; }
        float h[SW];
#pragma unroll
        for (int c = 0; c < SW; c++)
            h[c] = silu_f(fmaf(Sv, swc_w1[c], fmaf(Ev, swc_w1[SW + c], bc[c])));
#pragma unroll
        for (int c2 = 0; c2 < SW; c2++) {
            float o = swc_b2[c2];
#pragma unroll
            for (int c = 0; c < SW; c++) o = fmaf(h[c], swc_w2[c * SW + c2], o);
            oc[c2] = silu_f(o);
        }
    }

    // ---- agg[p] = sum_k wgt*oc[p] via LDS transpose + 2 shuffles ----
    __syncthreads();
#pragma unroll
    for (int p = 0; p < SW; p++) trn[tid * 17 + p] = wgt * oc[p];
    __syncthreads();
    {
        const int p = tid & 15, g = tid >> 4;
        float s = 0.f;
#pragma unroll
        for (int i = 0; i < 16; i++) s += trn[(g * 16 + i) * 17 + p];
        s += __shfl_xor(s, 16, 64);
        s += __shfl_xor(s, 32, 64);
        if (lane < 16) aggp[wid][p] = s;
    }
    __syncthreads();
    if (tid < 16)
        agg_ws[((size_t)b * Tn + t) * 16 + tid] =
            aggp[0][tid] + aggp[1][tid] + aggp[2][tid] + aggp[3][tid];
}

// ---------------- C2: up = W@V + agg@lin_e + b -> LN ----------------
__global__ __launch_bounds__(256) void up_kernel(
    const float* __restrict__ V,
    const float* __restrict__ agg_ws, const int* __restrict__ len_ws,
    const float* __restrict__ lin_e_w, const float* __restrict__ lin_e_b,
    const float* __restrict__ ln_o_g, const float* __restrict__ ln_o_b,
    float* __restrict__ out)
{
    const int t0 = blockIdx.x * 8, b = blockIdx.y, tid = threadIdx.x;
    const int tl = tid >> 5, rg = tid & 31, r0 = rg * 8;
    __shared__ float Wl[8 * 256];
    __shared__ float agg_l[8][16];

    {   // stage W tile (8 t-rows)
        const float4* s4 = (const float4*)(out + W_OFF + ((size_t)b * Tn + t0) * Kn);
        float4* d4 = (float4*)Wl;
        d4[tid * 2] = s4[tid * 2];
        d4[tid * 2 + 1] = s4[tid * 2 + 1];
    }
    if (tid < 128)
        agg_l[tid >> 4][tid & 15] =
            agg_ws[((size_t)b * Tn + t0 + (tid >> 4)) * 16 + (tid & 15)];
    __syncthreads();

    const int len = len_ws[b];
    const int t = t0 + tl;

    float acc[8];
#pragma unroll
    for (int j = 0; j < 8; j++) acc[j] = 0.f;

    const float* Vb = V + (size_t)(b * Kn) * Rn + r0;
    const float2* Wrow = (const float2*)(Wl + tl * 256);
#pragma unroll 4
    for (int k2 = 0; k2 < 128; k2++) {
        const float2 w2v = Wrow[k2];
        const float* va = Vb + (size_t)(2 * k2) * Rn;
        const float* vb = va + Rn;
        const float4 a0 = *(const float4*)(va);
        const float4 a1 = *(const float4*)(va + 4);
        const float4 b0 = *(const float4*)(vb);
        const float4 b1 = *(const float4*)(vb + 4);
        acc[0] = fmaf(w2v.x, a0.x, fmaf(w2v.y, b0.x, acc[0]));
        acc[1] = fmaf(w2v.x, a0.y, fmaf(w2v.y, b0.y, acc[1]));
        acc[2] = fmaf(w2v.x, a0.z, fmaf(w2v.y, b0.z, acc[2]));
        acc[3] = fmaf(w2v.x, a0.w, fmaf(w2v.y, b0.w, acc[3]));
        acc[4] = fmaf(w2v.x, a1.x, fmaf(w2v.y, b1.x, acc[4]));
        acc[5] = fmaf(w2v.x, a1.y, fmaf(w2v.y, b1.y, acc[5]));
        acc[6] = fmaf(w2v.x, a1.z, fmaf(w2v.y, b1.z, acc[6]));
        acc[7] = fmaf(w2v.x, a1.w, fmaf(w2v.y, b1.w, acc[7]));
    }

    // aggE + bias
#pragma unroll
    for (int p = 0; p < 16; p++) {
        const float a = agg_l[tl][p];
        const float4 l0 = *(const float4*)(lin_e_w + p * Rn + r0);
        const float4 l1 = *(const float4*)(lin_e_w + p * Rn + r0 + 4);
        acc[0] = fmaf(a, l0.x, acc[0]); acc[1] = fmaf(a, l0.y, acc[1]);
        acc[2] = fmaf(a, l0.z, acc[2]); acc[3] = fmaf(a, l0.w, acc[3]);
        acc[4] = fmaf(a, l1.x, acc[4]); acc[5] = fmaf(a, l1.y, acc[5]);
        acc[6] = fmaf(a, l1.z, acc[6]); acc[7] = fmaf(a, l1.w, acc[7]);
    }
    {
        const float4 be0 = *(const float4*)(lin_e_b + r0);
        const float4 be1 = *(const float4*)(lin_e_b + r0 + 4);
        acc[0] += be0.x; acc[1] += be0.y; acc[2] += be0.z; acc[3] += be0.w;
        acc[4] += be1.x; acc[5] += be1.y; acc[6] += be1.z; acc[7] += be1.w;
    }

    // LN over r (32 lanes x 8 each)
    float s = ((acc[0] + acc[1]) + (acc[2] + acc[3])) + ((acc[4] + acc[5]) + (acc[6] + acc[7]));
#pragma unroll
    for (int off = 1; off <= 16; off <<= 1) s += __shfl_xor(s, off, 64);
    const float mu = s * (1.f / Rn);
    float var = 0.f;
#pragma unroll
    for (int j = 0; j < 8; j++) { const float d = acc[j] - mu; var = fmaf(d, d, var); }
#pragma unroll
    for (int off = 1; off <= 16; off <<= 1) var += __shfl_xor(var, off, 64);
    const float rs = rsqrtf(var * (1.f / Rn) + 1e-5f);

    const bool valid = t < len;
    const float4 g0 = *(const float4*)(ln_o_g + r0);
    const float4 g1 = *(const float4*)(ln_o_g + r0 + 4);
    const float4 bb0 = *(const float4*)(ln_o_b + r0);
    const float4 bb1 = *(const float4*)(ln_o_b + r0 + 4);
    float res[8];
    res[0] = (acc[0] - mu) * rs * g0.x + bb0.x;
    res[1] = (acc[1] - mu) * rs * g0.y + bb0.y;
    res[2] = (acc[2] - mu) * rs * g0.z + bb0.z;
    res[3] = (acc[3] - mu) * rs * g0.w + bb0.w;
    res[4] = (acc[4] - mu) * rs * g1.x + bb1.x;
    res[5] = (acc[5] - mu) * rs * g1.y + bb1.y;
    res[6] = (acc[6] - mu) * rs * g1.z + bb1.z;
    res[7] = (acc[7] - mu) * rs * g1.w + bb1.w;
    if (!valid) {
#pragma unroll
        for (int j = 0; j < 8; j++) res[j] = 0.f;
    }
    float* dst = out + ((size_t)b * Tn + t) * Rn + r0;
    *(float4*)(dst)     = make_float4(res[0], res[1], res[2], res[3]);
    *(float4*)(dst + 4) = make_float4(res[4], res[5], res[6], res[7]);
}

// ---------------- launch ----------------
extern "C" void kernel_launch(void* const* d_in, const int* in_sizes, int n_in,
                              void* d_out, int out_size, void* d_ws, size_t ws_size,
                              hipStream_t stream)
{
    const float* dur       = (const float*)d_in[0];
    const float* V         = (const float*)d_in[1];
    const unsigned char* text_mask = (const unsigned char*)d_in[3];
    const float* conv_c_w  = (const float*)d_in[4];
    const float* conv_c_b  = (const float*)d_in[5];
    const float* bn_c_g    = (const float*)d_in[6];
    const float* bn_c_b    = (const float*)d_in[7];
    const float* ln_c_g    = (const float*)d_in[8];
    const float* ln_c_b    = (const float*)d_in[9];
    const float* conv_w_w  = (const float*)d_in[10];
    const float* conv_w_b  = (const float*)d_in[11];
    const float* bn_w_g    = (const float*)d_in[12];
    const float* bn_w_b    = (const float*)d_in[13];
    const float* ln_w_g    = (const float*)d_in[14];
    const float* ln_w_b    = (const float*)d_in[15];
    const float* swc_w1    = (const float*)d_in[16];
    const float* swc_b1    = (const float*)d_in[17];
    const float* swc_w2    = (const float*)d_in[18];
    const float* swc_b2    = (const float*)d_in[19];
    const float* sww_w1    = (const float*)d_in[20];
    const float* sww_b1    = (const float*)d_in[21];
    const float* sww_w2    = (const float*)d_in[22];
    const float* sww_b2    = (const float*)d_in[23];
    const float* proj_w_w  = (const float*)d_in[24];
    const float* proj_w_b  = (const float*)d_in[25];
    const float* lin_e_w   = (const float*)d_in[26];
    const float* lin_e_b   = (const float*)d_in[27];
    const float* ln_o_g    = (const float*)d_in[28];
    const float* ln_o_b    = (const float*)d_in[29];

    float* out = (float*)d_out;
    float* wsf = (float*)d_ws;
    float* s_k    = wsf;                       // 4096
    float* e_k    = wsf + 4096;                // 4096
    int*   len_ws = (int*)(wsf + 8192);        // 16 (pad 64)
    float* base_w = wsf + 8192 + 64;           // 65536
    float* base_c = base_w + 65536;            // 65536
    float* scratch = base_c + 65536;           // aliased: part (524288) then agg (256000)
    float* part   = scratch;
    float* agg_ws = scratch;

    scan_kernel<<<dim3(Bn), dim3(Kn), 0, stream>>>(dur, s_k, e_k, len_ws, out);
    conv_partial_kernel<<<dim3(8, Bn), dim3(256), 0, stream>>>(V, conv_w_w, conv_c_w, part);
    conv_finish_kernel<<<dim3(Bn), dim3(256), 0, stream>>>(
        part,
        conv_w_b, bn_w_g, bn_w_b, ln_w_g, ln_w_b,
        conv_c_b, bn_c_g, bn_c_b, ln_c_g, ln_c_b,
        sww_w1, sww_b1, swc_w1, swc_b1,
        base_w, base_c);
    logits_kernel<<<dim3(Tn, Bn), dim3(256), 0, stream>>>(
        text_mask, s_k, e_k, len_ws, base_w, base_c,
        sww_w1, sww_w2, sww_b2, proj_w_w, proj_w_b,
        swc_w1, swc_w2, swc_b2,
        agg_ws, out);
    up_kernel<<<dim3(Tn / 8, Bn), dim3(256), 0, stream>>>(
        V, agg_ws, len_ws, lin_e_w, lin_e_b, ln_o_g, ln_o_b, out);
}

// Round 3
// 214.077 us; speedup vs baseline: 3.1894x; 1.2487x over previous
//
#include <hip/hip_runtime.h>
#include <cstddef>

constexpr int Bn = 16, Kn = 256, Rn = 256, Tn = 1000, C8 = 8, SW = 16;
constexpr size_t UP_SZ    = (size_t)Bn * Tn * Rn;          // 4,096,000
constexpr size_t MASK_OFF = UP_SZ;                          // + 16,000
constexpr size_t LEN_OFF  = MASK_OFF + (size_t)Bn * Tn;     // + 16
constexpr size_t W_OFF    = LEN_OFF + Bn;                    // + 4,096,000

__device__ __forceinline__ float fast_rcp(float x) { return __builtin_amdgcn_rcpf(x); }
__device__ __forceinline__ float fast_exp2(float x) { return __builtin_amdgcn_exp2f(x); }
constexpr float LOG2E = 1.44269504088896340736f;
__device__ __forceinline__ float silu_f(float x) {
    return x * fast_rcp(1.f + fast_exp2(-LOG2E * x));
}

// ---------------- Kernel A: per-batch scan, length, mask ----------------
__global__ __launch_bounds__(256) void scan_kernel(
    const float* __restrict__ dur,
    float* __restrict__ s_k, float* __restrict__ e_k, int* __restrict__ len_ws,
    float* __restrict__ out)
{
    const int b = blockIdx.x, tid = threadIdx.x;
    __shared__ float sc[Kn];
    const float d = dur[b * Kn + tid];
    sc[tid] = d;
    __syncthreads();
    for (int off = 1; off < Kn; off <<= 1) {
        float v = (tid >= off) ? sc[tid - off] : 0.f;
        __syncthreads();
        sc[tid] += v;
        __syncthreads();
    }
    const float e = sc[tid];
    e_k[b * Kn + tid] = e;
    s_k[b * Kn + tid] = e - d;
    const float total = sc[Kn - 1];
    int len = (int)rintf(total);
    if (len > Tn) len = Tn;
    if (tid == 0) { len_ws[b] = len; out[LEN_OFF + b] = (float)len; }
    for (int t = tid; t < Tn; t += 256)
        out[MASK_OFF + (size_t)b * Tn + t] = (t >= len) ? 1.f : 0.f;
}

// ---------------- conv phase A: partial sums over r-chunks ----------------
__global__ __launch_bounds__(256) void conv_partial_kernel(
    const float* __restrict__ V,
    const float* __restrict__ wW, const float* __restrict__ wC,
    float* __restrict__ part)
{
    const int rc = blockIdx.x, b = blockIdx.y, k = threadIdx.x;
    constexpr int RPAD = 33;
    __shared__ float vt[258 * RPAD];
    if (k < 16) {
        const int row = (k < 8) ? 0 : 257;
        const int j = (k & 7) * 4;
        vt[row * RPAD + j] = 0.f; vt[row * RPAD + j + 1] = 0.f;
        vt[row * RPAD + j + 2] = 0.f; vt[row * RPAD + j + 3] = 0.f;
    }
    const float* vsrc = V + ((size_t)(b * Kn + k)) * Rn + rc * 32;
#pragma unroll
    for (int j = 0; j < 8; j++) {
        const float4 q = *(const float4*)(vsrc + j * 4);
        float* dst = &vt[(k + 1) * RPAD + j * 4];
        dst[0] = q.x; dst[1] = q.y; dst[2] = q.z; dst[3] = q.w;
    }
    __syncthreads();

    float aw[C8], ac[C8];
#pragma unroll
    for (int c = 0; c < C8; c++) { aw[c] = 0.f; ac[c] = 0.f; }
    for (int dk = 0; dk < 3; dk++) {
        const float* wp = wW + (size_t)(dk * Rn + rc * 32) * C8;
        const float* cp = wC + (size_t)(dk * Rn + rc * 32) * C8;
        const float* vrow = &vt[(k + dk) * RPAD];
#pragma unroll 4
        for (int r = 0; r < 32; r++) {
            const float v = vrow[r];
#pragma unroll
            for (int c = 0; c < C8; c++) {
                aw[c] = fmaf(v, wp[r * C8 + c], aw[c]);
                ac[c] = fmaf(v, cp[r * C8 + c], ac[c]);
            }
        }
    }
    float* dst = part + ((size_t)(b * 8 + rc) * Kn + k) * 16;
    *(float4*)(dst + 0)  = make_float4(aw[0], aw[1], aw[2], aw[3]);
    *(float4*)(dst + 4)  = make_float4(aw[4], aw[5], aw[6], aw[7]);
    *(float4*)(dst + 8)  = make_float4(ac[0], ac[1], ac[2], ac[3]);
    *(float4*)(dst + 12) = make_float4(ac[4], ac[5], ac[6], ac[7]);
}

// ---------------- conv phase B: reduce partials + post + base ----------------
__device__ __forceinline__ void conv_post(
    const float* acc, const float* cb, const float* bng, const float* bnb,
    const float* lng, const float* lnb, const float* w1, const float* b1,
    float* __restrict__ dst)
{
    const float bnscale = rsqrtf(1.f + 1e-5f);
    float x[C8];
    float mu = 0.f;
#pragma unroll
    for (int c = 0; c < C8; c++) {
        float v = (acc[c] + cb[c]) * (bng[c] * bnscale) + bnb[c];
        v = silu_f(v);
        x[c] = v; mu += v;
    }
    mu *= (1.f / C8);
    float var = 0.f;
#pragma unroll
    for (int c = 0; c < C8; c++) { float dd = x[c] - mu; var += dd * dd; }
    var *= (1.f / C8);
    const float rs = rsqrtf(var + 1e-5f);
    float y[C8];
#pragma unroll
    for (int c = 0; c < C8; c++) y[c] = (x[c] - mu) * rs * lng[c] + lnb[c];
#pragma unroll
    for (int c2 = 0; c2 < SW; c2++) {
        float a = b1[c2];
#pragma unroll
        for (int p = 0; p < C8; p++) a = fmaf(y[p], w1[(2 + p) * SW + c2], a);
        dst[c2] = a;
    }
}

__global__ __launch_bounds__(256) void conv_finish_kernel(
    const float* __restrict__ part,
    const float* __restrict__ bW, const float* __restrict__ bngW, const float* __restrict__ bnbW,
    const float* __restrict__ lngW, const float* __restrict__ lnbW,
    const float* __restrict__ bC, const float* __restrict__ bngC, const float* __restrict__ bnbC,
    const float* __restrict__ lngC, const float* __restrict__ lnbC,
    const float* __restrict__ sww_w1, const float* __restrict__ sww_b1,
    const float* __restrict__ swc_w1, const float* __restrict__ swc_b1,
    float* __restrict__ base_w, float* __restrict__ base_c)
{
    const int b = blockIdx.x, k = threadIdx.x;
    float aw[C8], ac[C8];
#pragma unroll
    for (int c = 0; c < C8; c++) { aw[c] = 0.f; ac[c] = 0.f; }
#pragma unroll 2
    for (int rc = 0; rc < 8; rc++) {
        const float4* p = (const float4*)(part + ((size_t)(b * 8 + rc) * Kn + k) * 16);
        const float4 q0 = p[0], q1 = p[1], q2 = p[2], q3 = p[3];
        aw[0] += q0.x; aw[1] += q0.y; aw[2] += q0.z; aw[3] += q0.w;
        aw[4] += q1.x; aw[5] += q1.y; aw[6] += q1.z; aw[7] += q1.w;
        ac[0] += q2.x; ac[1] += q2.y; ac[2] += q2.z; ac[3] += q2.w;
        ac[4] += q3.x; ac[5] += q3.y; ac[6] += q3.z; ac[7] += q3.w;
    }
    conv_post(aw, bW, bngW, bnbW, lngW, lnbW, sww_w1, sww_b1,
              base_w + ((size_t)(b * Kn) + k) * SW);
    conv_post(ac, bC, bngC, bnbC, lngC, lnbC, swc_w1, swc_b1,
              base_c + ((size_t)(b * Kn) + k) * SW);
}

// ---------------- C1: swish blocks + softmax + W + agg (2 t per block) ----------------
__global__ __launch_bounds__(256) void logits_kernel(
    const unsigned char* __restrict__ text_mask,
    const float* __restrict__ s_k, const float* __restrict__ e_k,
    const int* __restrict__ len_ws,
    const float* __restrict__ base_w, const float* __restrict__ base_c,
    const float* __restrict__ sww_w1, const float* __restrict__ sww_w2, const float* __restrict__ sww_b2,
    const float* __restrict__ proj_w, const float* __restrict__ proj_b,
    const float* __restrict__ swc_w1, const float* __restrict__ swc_w2, const float* __restrict__ swc_b2,
    float* __restrict__ agg_ws,
    float* __restrict__ out)
{
    const int t0 = blockIdx.x * 2, b = blockIdx.y, tid = threadIdx.x;
    const int len = len_ws[b];

    __shared__ float trn[Kn * 17];
    __shared__ float red[4];
    __shared__ float aggp[4][16];

    const int lane = tid & 63, wid = tid >> 6;
    const bool tmask = text_mask[b * Kn + tid] != 0;
    const float skv = s_k[b * Kn + tid], ekv = e_k[b * Kn + tid];

    // hoisted base vectors (shared by both t's)
    float bw[SW], bc[SW];
    {
        const float4* bp = (const float4*)(base_w + ((size_t)(b * Kn) + tid) * SW);
        float4 q0 = bp[0], q1 = bp[1], q2 = bp[2], q3 = bp[3];
        bw[0]=q0.x; bw[1]=q0.y; bw[2]=q0.z; bw[3]=q0.w;
        bw[4]=q1.x; bw[5]=q1.y; bw[6]=q1.z; bw[7]=q1.w;
        bw[8]=q2.x; bw[9]=q2.y; bw[10]=q2.z; bw[11]=q2.w;
        bw[12]=q3.x; bw[13]=q3.y; bw[14]=q3.z; bw[15]=q3.w;
    }
    {
        const float4* bp = (const float4*)(base_c + ((size_t)(b * Kn) + tid) * SW);
        float4 q0 = bp[0], q1 = bp[1], q2 = bp[2], q3 = bp[3];
        bc[0]=q0.x; bc[1]=q0.y; bc[2]=q0.z; bc[3]=q0.w;
        bc[4]=q1.x; bc[5]=q1.y; bc[6]=q1.z; bc[7]=q1.w;
        bc[8]=q2.x; bc[9]=q2.y; bc[10]=q2.z; bc[11]=q2.w;
        bc[12]=q3.x; bc[13]=q3.y; bc[14]=q3.z; bc[15]=q3.w;
    }

    for (int ti = 0; ti < 2; ti++) {
        const int t = t0 + ti;
        float* __restrict__ W_out = out + W_OFF + ((size_t)b * Tn + t) * Kn;
        if (t >= len) { W_out[tid] = 0.f; continue; }   // uniform across block

        const float tv = (float)(t + 1);
        const float Sv = tmask ? 0.f : tv - skv;
        const float Ev = tmask ? 0.f : ekv - tv;

        // ---- W swish block -> logit ----
        float logit;
        {
            float h[SW];
#pragma unroll
            for (int c = 0; c < SW; c++)
                h[c] = silu_f(fmaf(Sv, sww_w1[c], fmaf(Ev, sww_w1[SW + c], bw[c])));
            float acc = proj_b[0];
#pragma unroll
            for (int c2 = 0; c2 < SW; c2++) {
                float o = sww_b2[c2];
#pragma unroll
                for (int c = 0; c < SW; c++) o = fmaf(h[c], sww_w2[c * SW + c2], o);
                acc = fmaf(silu_f(o), proj_w[c2], acc);
            }
            logit = tmask ? -INFINITY : acc;
        }

        // ---- softmax over K ----
        float m = logit;
#pragma unroll
        for (int off = 32; off >= 1; off >>= 1) m = fmaxf(m, __shfl_xor(m, off, 64));
        if (lane == 0) red[wid] = m;
        __syncthreads();
        m = fmaxf(fmaxf(red[0], red[1]), fmaxf(red[2], red[3]));
        __syncthreads();
        const float pex = fast_exp2(LOG2E * (logit - m));
        float ssum = pex;
#pragma unroll
        for (int off = 32; off >= 1; off >>= 1) ssum += __shfl_xor(ssum, off, 64);
        if (lane == 0) red[wid] = ssum;
        __syncthreads();
        ssum = red[0] + red[1] + red[2] + red[3];
        const float wgt = pex * fast_rcp(ssum);
        W_out[tid] = wgt;

        // ---- C swish block ----
        float oc[SW];
        {
            float h[SW];
#pragma unroll
            for (int c = 0; c < SW; c++)
                h[c] = silu_f(fmaf(Sv, swc_w1[c], fmaf(Ev, swc_w1[SW + c], bc[c])));
#pragma unroll
            for (int c2 = 0; c2 < SW; c2++) {
                float o = swc_b2[c2];
#pragma unroll
                for (int c = 0; c < SW; c++) o = fmaf(h[c], swc_w2[c * SW + c2], o);
                oc[c2] = silu_f(o);
            }
        }

        // ---- agg[p] = sum_k wgt*oc[p] via LDS transpose + 2 shuffles ----
        __syncthreads();
#pragma unroll
        for (int p = 0; p < SW; p++) trn[tid * 17 + p] = wgt * oc[p];
        __syncthreads();
        {
            const int p = tid & 15, g = tid >> 4;
            float s = 0.f;
#pragma unroll
            for (int i = 0; i < 16; i++) s += trn[(g * 16 + i) * 17 + p];
            s += __shfl_xor(s, 16, 64);
            s += __shfl_xor(s, 32, 64);
            if (lane < 16) aggp[wid][p] = s;
        }
        __syncthreads();
        if (tid < 16)
            agg_ws[((size_t)b * Tn + t) * 16 + tid] =
                aggp[0][tid] + aggp[1][tid] + aggp[2][tid] + aggp[3][tid];
        __syncthreads();
    }
}

// ---------------- C2: raw = W@V  (LDS-tiled, 64t x 64r x 256k per block) ----------------
__global__ __launch_bounds__(256) void matvec_kernel(
    const float* __restrict__ V, const float* __restrict__ Wg,
    float* __restrict__ out)
{
    const int tb = blockIdx.x, rq = blockIdx.y, b = blockIdx.z;
    const int t0 = tb * 64, r0 = rq * 64;
    const int tid = threadIdx.x;
    __shared__ float4 Wl[64 * 64];   // [tt][k4]  64 KiB
    __shared__ float4 Vl[256 * 16];  // [k][q]    64 KiB

    const float4* Wg4 = (const float4*)Wg;
#pragma unroll
    for (int ch = 0; ch < 16; ch++) {
        const int idx = ch * 256 + tid;
        const int tt = idx >> 6, c4 = idx & 63;
        const int t = t0 + tt;
        Wl[idx] = (t < Tn) ? Wg4[(((size_t)b * Tn + t) * Kn >> 2) + c4]
                           : make_float4(0.f, 0.f, 0.f, 0.f);
    }
    const float4* V4 = (const float4*)V;
#pragma unroll
    for (int ch = 0; ch < 16; ch++) {
        const int idx = ch * 256 + tid;
        const int k = idx >> 4, q = idx & 15;
        Vl[idx] = V4[(((size_t)b * Kn + k) * Rn >> 2) + (r0 >> 2) + q];
    }
    __syncthreads();

    const int tg = tid >> 4, rg = tid & 15;
    float4 acc[4];
#pragma unroll
    for (int i = 0; i < 4; i++) acc[i] = make_float4(0.f, 0.f, 0.f, 0.f);

    for (int k4 = 0; k4 < 64; k4++) {
        const float4 v0 = Vl[(k4 * 4 + 0) * 16 + rg];
        const float4 v1 = Vl[(k4 * 4 + 1) * 16 + rg];
        const float4 v2 = Vl[(k4 * 4 + 2) * 16 + rg];
        const float4 v3 = Vl[(k4 * 4 + 3) * 16 + rg];
#pragma unroll
        for (int i = 0; i < 4; i++) {
            const float4 wv = Wl[(tg * 4 + i) * 64 + k4];
            acc[i].x = fmaf(wv.x, v0.x, acc[i].x);
            acc[i].y = fmaf(wv.x, v0.y, acc[i].y);
            acc[i].z = fmaf(wv.x, v0.z, acc[i].z);
            acc[i].w = fmaf(wv.x, v0.w, acc[i].w);
            acc[i].x = fmaf(wv.y, v1.x, acc[i].x);
            acc[i].y = fmaf(wv.y, v1.y, acc[i].y);
            acc[i].z = fmaf(wv.y, v1.z, acc[i].z);
            acc[i].w = fmaf(wv.y, v1.w, acc[i].w);
            acc[i].x = fmaf(wv.z, v2.x, acc[i].x);
            acc[i].y = fmaf(wv.z, v2.y, acc[i].y);
            acc[i].z = fmaf(wv.z, v2.z, acc[i].z);
            acc[i].w = fmaf(wv.z, v2.w, acc[i].w);
            acc[i].x = fmaf(wv.w, v3.x, acc[i].x);
            acc[i].y = fmaf(wv.w, v3.y, acc[i].y);
            acc[i].z = fmaf(wv.w, v3.z, acc[i].z);
            acc[i].w = fmaf(wv.w, v3.w, acc[i].w);
        }
    }

#pragma unroll
    for (int i = 0; i < 4; i++) {
        const int t = t0 + tg * 4 + i;
        if (t < Tn)
            *(float4*)(out + ((size_t)b * Tn + t) * Rn + r0 + rg * 4) = acc[i];
    }
}

// ---------------- C3: finish: up = raw + agg@lin_e + b -> LN, mask ----------------
__global__ __launch_bounds__(256) void ln_kernel(
    const float* __restrict__ agg_ws, const int* __restrict__ len_ws,
    const float* __restrict__ lin_e_w, const float* __restrict__ lin_e_b,
    const float* __restrict__ ln_o_g, const float* __restrict__ ln_o_b,
    float* __restrict__ out)
{
    const int t = blockIdx.x, b = blockIdx.y, r = threadIdx.x;
    float* __restrict__ row = out + ((size_t)b * Tn + t) * Rn;
    const int len = len_ws[b];
    if (t >= len) { row[r] = 0.f; return; }

    __shared__ float agg_l[16];
    __shared__ float red[4];
    if (r < 16) agg_l[r] = agg_ws[((size_t)b * Tn + t) * 16 + r];
    const float raw = row[r];
    __syncthreads();

    float acc = raw + lin_e_b[r];
#pragma unroll
    for (int p = 0; p < 16; p++) acc = fmaf(agg_l[p], lin_e_w[p * Rn + r], acc);

    const int lane = r & 63, wid = r >> 6;
    float s = acc;
#pragma unroll
    for (int off = 32; off >= 1; off >>= 1) s += __shfl_xor(s, off, 64);
    if (lane == 0) red[wid] = s;
    __syncthreads();
    s = red[0] + red[1] + red[2] + red[3];
    __syncthreads();
    const float mu = s * (1.f / Rn);
    const float dv = acc - mu;
    float vr = dv * dv;
#pragma unroll
    for (int off = 32; off >= 1; off >>= 1) vr += __shfl_xor(vr, off, 64);
    if (lane == 0) red[wid] = vr;
    __syncthreads();
    vr = (red[0] + red[1] + red[2] + red[3]) * (1.f / Rn);
    row[r] = dv * rsqrtf(vr + 1e-5f) * ln_o_g[r] + ln_o_b[r];
}

// ---------------- launch ----------------
extern "C" void kernel_launch(void* const* d_in, const int* in_sizes, int n_in,
                              void* d_out, int out_size, void* d_ws, size_t ws_size,
                              hipStream_t stream)
{
    const float* dur       = (const float*)d_in[0];
    const float* V         = (const float*)d_in[1];
    const unsigned char* text_mask = (const unsigned char*)d_in[3];
    const float* conv_c_w  = (const float*)d_in[4];
    const float* conv_c_b  = (const float*)d_in[5];
    const float* bn_c_g    = (const float*)d_in[6];
    const float* bn_c_b    = (const float*)d_in[7];
    const float* ln_c_g    = (const float*)d_in[8];
    const float* ln_c_b    = (const float*)d_in[9];
    const float* conv_w_w  = (const float*)d_in[10];
    const float* conv_w_b  = (const float*)d_in[11];
    const float* bn_w_g    = (const float*)d_in[12];
    const float* bn_w_b    = (const float*)d_in[13];
    const float* ln_w_g    = (const float*)d_in[14];
    const float* ln_w_b    = (const float*)d_in[15];
    const float* swc_w1    = (const float*)d_in[16];
    const float* swc_b1    = (const float*)d_in[17];
    const float* swc_w2    = (const float*)d_in[18];
    const float* swc_b2    = (const float*)d_in[19];
    const float* sww_w1    = (const float*)d_in[20];
    const float* sww_b1    = (const float*)d_in[21];
    const float* sww_w2    = (const float*)d_in[22];
    const float* sww_b2    = (const float*)d_in[23];
    const float* proj_w_w  = (const float*)d_in[24];
    const float* proj_w_b  = (const float*)d_in[25];
    const float* lin_e_w   = (const float*)d_in[26];
    const float* lin_e_b   = (const float*)d_in[27];
    const float* ln_o_g    = (const float*)d_in[28];
    const float* ln_o_b    = (const float*)d_in[29];

    float* out = (float*)d_out;
    float* wsf = (float*)d_ws;
    float* s_k    = wsf;                       // 4096
    float* e_k    = wsf + 4096;                // 4096
    int*   len_ws = (int*)(wsf + 8192);        // 16 (pad 64)
    float* base_w = wsf + 8192 + 64;           // 65536
    float* base_c = base_w + 65536;            // 65536
    float* scratch = base_c + 65536;           // aliased: part (524288) then agg (256000)
    float* part   = scratch;
    float* agg_ws = scratch;

    scan_kernel<<<dim3(Bn), dim3(Kn), 0, stream>>>(dur, s_k, e_k, len_ws, out);
    conv_partial_kernel<<<dim3(8, Bn), dim3(256), 0, stream>>>(V, conv_w_w, conv_c_w, part);
    conv_finish_kernel<<<dim3(Bn), dim3(256), 0, stream>>>(
        part,
        conv_w_b, bn_w_g, bn_w_b, ln_w_g, ln_w_b,
        conv_c_b, bn_c_g, bn_c_b, ln_c_g, ln_c_b,
        sww_w1, sww_b1, swc_w1, swc_b1,
        base_w, base_c);
    logits_kernel<<<dim3(Tn / 2, Bn), dim3(256), 0, stream>>>(
        text_mask, s_k, e_k, len_ws, base_w, base_c,
        sww_w1, sww_w2, sww_b2, proj_w_w, proj_w_b,
        swc_w1, swc_w2, swc_b2,
        agg_ws, out);
    matvec_kernel<<<dim3(16, 4, Bn), dim3(256), 0, stream>>>(
        V, out + W_OFF, out);
    ln_kernel<<<dim3(Tn, Bn), dim3(256), 0, stream>>>(
        agg_ws, len_ws, lin_e_w, lin_e_b, ln_o_g, ln_o_b, out);
}

// Round 5
// 197.848 us; speedup vs baseline: 3.4510x; 1.0820x over previous
//
#include <hip/hip_runtime.h>
#include <cstddef>

constexpr int Bn = 16, Kn = 256, Rn = 256, Tn = 1000, C8 = 8, SW = 16;
constexpr size_t UP_SZ    = (size_t)Bn * Tn * Rn;          // 4,096,000
constexpr size_t MASK_OFF = UP_SZ;                          // + 16,000
constexpr size_t LEN_OFF  = MASK_OFF + (size_t)Bn * Tn;     // + 16
constexpr size_t W_OFF    = LEN_OFF + Bn;                    // + 4,096,000

using half4_t = __attribute__((ext_vector_type(4))) _Float16;
using f32x4_t = __attribute__((ext_vector_type(4))) float;
using uint2_t = __attribute__((ext_vector_type(2))) unsigned int;

__device__ __forceinline__ float fast_rcp(float x) { return __builtin_amdgcn_rcpf(x); }
__device__ __forceinline__ float fast_exp2(float x) { return __builtin_amdgcn_exp2f(x); }
constexpr float LOG2E = 1.44269504088896340736f;
__device__ __forceinline__ float silu_f(float x) {
    return x * fast_rcp(1.f + fast_exp2(-LOG2E * x));
}

// ---------------- Kernel A: per-batch scan, length, mask ----------------
__global__ __launch_bounds__(256) void scan_kernel(
    const float* __restrict__ dur,
    float* __restrict__ s_k, float* __restrict__ e_k, int* __restrict__ len_ws,
    float* __restrict__ out)
{
    const int b = blockIdx.x, tid = threadIdx.x;
    __shared__ float sc[Kn];
    const float d = dur[b * Kn + tid];
    sc[tid] = d;
    __syncthreads();
    for (int off = 1; off < Kn; off <<= 1) {
        float v = (tid >= off) ? sc[tid - off] : 0.f;
        __syncthreads();
        sc[tid] += v;
        __syncthreads();
    }
    const float e = sc[tid];
    e_k[b * Kn + tid] = e;
    s_k[b * Kn + tid] = e - d;
    const float total = sc[Kn - 1];
    int len = (int)rintf(total);
    if (len > Tn) len = Tn;
    if (tid == 0) { len_ws[b] = len; out[LEN_OFF + b] = (float)len; }
    for (int t = tid; t < Tn; t += 256)
        out[MASK_OFF + (size_t)b * Tn + t] = (t >= len) ? 1.f : 0.f;
}

// ---------------- conv phase A: partial sums over r-chunks ----------------
__global__ __launch_bounds__(256) void conv_partial_kernel(
    const float* __restrict__ V,
    const float* __restrict__ wW, const float* __restrict__ wC,
    float* __restrict__ part)
{
    const int rc = blockIdx.x, b = blockIdx.y, k = threadIdx.x;
    constexpr int RPAD = 33;
    __shared__ float vt[258 * RPAD];
    if (k < 16) {
        const int row = (k < 8) ? 0 : 257;
        const int j = (k & 7) * 4;
        vt[row * RPAD + j] = 0.f; vt[row * RPAD + j + 1] = 0.f;
        vt[row * RPAD + j + 2] = 0.f; vt[row * RPAD + j + 3] = 0.f;
    }
    const float* vsrc = V + ((size_t)(b * Kn + k)) * Rn + rc * 32;
#pragma unroll
    for (int j = 0; j < 8; j++) {
        const float4 q = *(const float4*)(vsrc + j * 4);
        float* dst = &vt[(k + 1) * RPAD + j * 4];
        dst[0] = q.x; dst[1] = q.y; dst[2] = q.z; dst[3] = q.w;
    }
    __syncthreads();

    float aw[C8], ac[C8];
#pragma unroll
    for (int c = 0; c < C8; c++) { aw[c] = 0.f; ac[c] = 0.f; }
    for (int dk = 0; dk < 3; dk++) {
        const float* wp = wW + (size_t)(dk * Rn + rc * 32) * C8;
        const float* cp = wC + (size_t)(dk * Rn + rc * 32) * C8;
        const float* vrow = &vt[(k + dk) * RPAD];
#pragma unroll 4
        for (int r = 0; r < 32; r++) {
            const float v = vrow[r];
#pragma unroll
            for (int c = 0; c < C8; c++) {
                aw[c] = fmaf(v, wp[r * C8 + c], aw[c]);
                ac[c] = fmaf(v, cp[r * C8 + c], ac[c]);
            }
        }
    }
    float* dst = part + ((size_t)(b * 8 + rc) * Kn + k) * 16;
    *(float4*)(dst + 0)  = make_float4(aw[0], aw[1], aw[2], aw[3]);
    *(float4*)(dst + 4)  = make_float4(aw[4], aw[5], aw[6], aw[7]);
    *(float4*)(dst + 8)  = make_float4(ac[0], ac[1], ac[2], ac[3]);
    *(float4*)(dst + 12) = make_float4(ac[4], ac[5], ac[6], ac[7]);
}

// ---------------- conv phase B: reduce + post + alpha/beta precompute ----------------
__device__ __forceinline__ void conv_post(
    const float* acc, const float* cb, const float* bng, const float* bnb,
    const float* lng, const float* lnb, const float* w1, const float* b1,
    float* __restrict__ dst)
{
    const float bnscale = rsqrtf(1.f + 1e-5f);
    float x[C8];
    float mu = 0.f;
#pragma unroll
    for (int c = 0; c < C8; c++) {
        float v = (acc[c] + cb[c]) * (bng[c] * bnscale) + bnb[c];
        v = silu_f(v);
        x[c] = v; mu += v;
    }
    mu *= (1.f / C8);
    float var = 0.f;
#pragma unroll
    for (int c = 0; c < C8; c++) { float dd = x[c] - mu; var += dd * dd; }
    var *= (1.f / C8);
    const float rs = rsqrtf(var + 1e-5f);
    float y[C8];
#pragma unroll
    for (int c = 0; c < C8; c++) y[c] = (x[c] - mu) * rs * lng[c] + lnb[c];
#pragma unroll
    for (int c2 = 0; c2 < SW; c2++) {
        float a = b1[c2];
#pragma unroll
        for (int p = 0; p < C8; p++) a = fmaf(y[p], w1[(2 + p) * SW + c2], a);
        dst[c2] = a;
    }
}

__global__ __launch_bounds__(256) void conv_finish_kernel(
    const float* __restrict__ part,
    const unsigned char* __restrict__ tmask_g,
    const float* __restrict__ s_k, const float* __restrict__ e_k,
    const float* __restrict__ bW, const float* __restrict__ bngW, const float* __restrict__ bnbW,
    const float* __restrict__ lngW, const float* __restrict__ lnbW,
    const float* __restrict__ bC, const float* __restrict__ bngC, const float* __restrict__ bnbC,
    const float* __restrict__ lngC, const float* __restrict__ lnbC,
    const float* __restrict__ sww_w1, const float* __restrict__ sww_b1,
    const float* __restrict__ swc_w1, const float* __restrict__ swc_b1,
    float* __restrict__ ab_ws)
{
    const int b = blockIdx.x, k = threadIdx.x;
    float aw[C8], ac[C8];
#pragma unroll
    for (int c = 0; c < C8; c++) { aw[c] = 0.f; ac[c] = 0.f; }
#pragma unroll 2
    for (int rc = 0; rc < 8; rc++) {
        const float4* p = (const float4*)(part + ((size_t)(b * 8 + rc) * Kn + k) * 16);
        const float4 q0 = p[0], q1 = p[1], q2 = p[2], q3 = p[3];
        aw[0] += q0.x; aw[1] += q0.y; aw[2] += q0.z; aw[3] += q0.w;
        aw[4] += q1.x; aw[5] += q1.y; aw[6] += q1.z; aw[7] += q1.w;
        ac[0] += q2.x; ac[1] += q2.y; ac[2] += q2.z; ac[3] += q2.w;
        ac[4] += q3.x; ac[5] += q3.y; ac[6] += q3.z; ac[7] += q3.w;
    }
    float basew[SW], basec[SW];
    conv_post(aw, bW, bngW, bnbW, lngW, lnbW, sww_w1, sww_b1, basew);
    conv_post(ac, bC, bngC, bnbC, lngC, lnbC, swc_w1, swc_b1, basec);

    const bool msk = tmask_g[b * Kn + k] != 0;
    const float sk = s_k[b * Kn + k], ek = e_k[b * Kn + k];
    float* dst = ab_ws + ((size_t)(b * Kn) + k) * 64;
#pragma unroll
    for (int c = 0; c < SW; c++) {
        const float w0w = sww_w1[c], w1w_ = sww_w1[SW + c];
        const float w0c = swc_w1[c], w1c_ = swc_w1[SW + c];
        dst[c]      = msk ? 0.f : (w0w - w1w_);
        dst[16 + c] = msk ? basew[c] : fmaf(ek, w1w_, fmaf(-sk, w0w, basew[c]));
        dst[32 + c] = msk ? 0.f : (w0c - w1c_);
        dst[48 + c] = msk ? basec[c] : fmaf(ek, w1c_, fmaf(-sk, w0c, basec[c]));
    }
}

// ---------------- C1: swish blocks via MFMA + softmax + W + agg ----------------
__global__ __launch_bounds__(256) void logits_kernel(
    const unsigned char* __restrict__ tm, const int* __restrict__ len_ws,
    const float* __restrict__ ab_ws,
    const float* __restrict__ sww_w2, const float* __restrict__ sww_b2,
    const float* __restrict__ proj_w, const float* __restrict__ proj_b,
    const float* __restrict__ swc_w2, const float* __restrict__ swc_b2,
    float* __restrict__ agg_ws, float* __restrict__ out)
{
    const int t0 = blockIdx.x * 2, b = blockIdx.y, tid = threadIdx.x;
    const int lane = tid & 63, w = tid >> 6, q = lane >> 4, m = lane & 15;
    const int len = len_ws[b];

    __shared__ unsigned int hA[256 * 10];   // 10240 B : h_w hi, then reused for h_c
    __shared__ unsigned int hB[256 * 10];   // 10240 B : h_w lo
    __shared__ float red[8];
    __shared__ float aggw[4][16];

    // ---- hoisted per-block state ----
    float aw[16], bw[16], acv[16], bcv[16];
    {
        const float4* abp = (const float4*)(ab_ws + (((size_t)b * Kn) + tid) * 64);
#pragma unroll
        for (int i = 0; i < 4; i++) {
            float4 v = abp[i];
            aw[4*i] = v.x; aw[4*i+1] = v.y; aw[4*i+2] = v.z; aw[4*i+3] = v.w;
        }
#pragma unroll
        for (int i = 0; i < 4; i++) {
            float4 v = abp[4 + i];
            bw[4*i] = v.x; bw[4*i+1] = v.y; bw[4*i+2] = v.z; bw[4*i+3] = v.w;
        }
#pragma unroll
        for (int i = 0; i < 4; i++) {
            float4 v = abp[8 + i];
            acv[4*i] = v.x; acv[4*i+1] = v.y; acv[4*i+2] = v.z; acv[4*i+3] = v.w;
        }
#pragma unroll
        for (int i = 0; i < 4; i++) {
            float4 v = abp[12 + i];
            bcv[4*i] = v.x; bcv[4*i+1] = v.y; bcv[4*i+2] = v.z; bcv[4*i+3] = v.w;
        }
    }

    // A-fragments: A = w2^T (uniform across block). lane l, reg i: w2[4q+i][m]
    half4_t AWhi, AWlo, ACf;
    float pj[4], b2wv[4], b2cv[4], mb[4];
#pragma unroll
    for (int i = 0; i < 4; i++) {
        const int c = 4 * q + i;
        const float vw = sww_w2[c * SW + m];
        const _Float16 hi = (_Float16)vw;
        AWhi[i] = hi;
        AWlo[i] = (_Float16)(vw - (float)hi);
        ACf[i]  = (_Float16)(swc_w2[c * SW + m]);
        pj[i]   = proj_w[c];
        b2wv[i] = sww_b2[c];
        b2cv[i] = swc_b2[c];
        mb[i]   = (tm[b * Kn + 64 * w + 16 * i + m] != 0) ? -INFINITY : 0.f;
    }
    const float pb = proj_b[0];

    for (int ti = 0; ti < 2; ti++) {
        const int t = t0 + ti;
        float* __restrict__ W_out = out + W_OFF + ((size_t)b * Tn + t) * Kn;
        if (t >= len) { W_out[tid] = 0.f; continue; }   // uniform over block
        const float u = (float)(t + 1);

        // ---- layer-1 + fp16 pack (thread = k row) ----
        unsigned int wh[8], wl[8], ch[8];
#pragma unroll
        for (int p = 0; p < 8; p++) {
            const float x0 = fmaf(u, aw[2*p],   bw[2*p]);
            const float x1 = fmaf(u, aw[2*p+1], bw[2*p+1]);
            const float h0 = silu_f(x0), h1 = silu_f(x1);
            const auto hp = __builtin_amdgcn_cvt_pkrtz(h0, h1);   // __fp16 x2
            wh[p] = __builtin_bit_cast(unsigned int, hp);
            const float l0 = h0 - (float)hp.x, l1 = h1 - (float)hp.y;
            wl[p] = __builtin_bit_cast(unsigned int, __builtin_amdgcn_cvt_pkrtz(l0, l1));
            const float y0 = fmaf(u, acv[2*p],   bcv[2*p]);
            const float y1 = fmaf(u, acv[2*p+1], bcv[2*p+1]);
            ch[p] = __builtin_bit_cast(unsigned int,
                     __builtin_amdgcn_cvt_pkrtz(silu_f(y0), silu_f(y1)));
        }
#pragma unroll
        for (int p = 0; p < 4; p++) {
            uint2_t a; a.x = wh[2*p]; a.y = wh[2*p+1];
            *(uint2_t*)&hA[tid * 10 + 2 * p] = a;
            uint2_t bb; bb.x = wl[2*p]; bb.y = wl[2*p+1];
            *(uint2_t*)&hB[tid * 10 + 2 * p] = bb;
        }
        // wave-local rows: in-wave DS ordering suffices (no barrier needed)

        // ---- MFMA W-path: o = w2^T @ h^T, split-fp16 (3 mfma per tile) ----
        f32x4_t o[4];
#pragma unroll
        for (int j = 0; j < 4; j++) {
            const int row = 64 * w + 16 * j + m;
            const uint2_t rh = *(const uint2_t*)&hA[row * 10 + 2 * q];
            const uint2_t rl = *(const uint2_t*)&hB[row * 10 + 2 * q];
            const half4_t bh = __builtin_bit_cast(half4_t, rh);
            const half4_t bl = __builtin_bit_cast(half4_t, rl);
            f32x4_t acc = {0.f, 0.f, 0.f, 0.f};
            acc = __builtin_amdgcn_mfma_f32_16x16x16f16(AWlo, bh, acc, 0, 0, 0);
            acc = __builtin_amdgcn_mfma_f32_16x16x16f16(AWhi, bl, acc, 0, 0, 0);
            acc = __builtin_amdgcn_mfma_f32_16x16x16f16(AWhi, bh, acc, 0, 0, 0);
            o[j] = acc;
        }

        // ---- logit: silu(o + b2) . proj, reduce over c2 ----
        float lg[4];
#pragma unroll
        for (int j = 0; j < 4; j++) {
            float s = silu_f(o[j][0] + b2wv[0]) * pj[0];
            s = fmaf(silu_f(o[j][1] + b2wv[1]), pj[1], s);
            s = fmaf(silu_f(o[j][2] + b2wv[2]), pj[2], s);
            s = fmaf(silu_f(o[j][3] + b2wv[3]), pj[3], s);
            s += __shfl_xor(s, 16, 64);
            s += __shfl_xor(s, 32, 64);
            lg[j] = s + pb + mb[j];
        }

        // ---- softmax over 256 rows ----
        float mx = fmaxf(fmaxf(lg[0], lg[1]), fmaxf(lg[2], lg[3]));
#pragma unroll
        for (int off = 1; off <= 8; off <<= 1) mx = fmaxf(mx, __shfl_xor(mx, off, 64));
        if (lane == 0) red[w] = mx;
        __syncthreads();                        // S2: publish wave maxima
        const float M = fmaxf(fmaxf(red[0], red[1]), fmaxf(red[2], red[3]));
        float pex[4];
#pragma unroll
        for (int j = 0; j < 4; j++) pex[j] = fast_exp2(LOG2E * (lg[j] - M));
        float ssum = (pex[0] + pex[1]) + (pex[2] + pex[3]);
#pragma unroll
        for (int off = 1; off <= 8; off <<= 1) ssum += __shfl_xor(ssum, off, 64);
        if (lane == 0) red[4 + w] = ssum;
        // stage h_c into hA (wave-local rows; ordered after this wave's reads)
#pragma unroll
        for (int p = 0; p < 4; p++) {
            uint2_t a; a.x = ch[2*p]; a.y = ch[2*p+1];
            *(uint2_t*)&hA[tid * 10 + 2 * p] = a;
        }
        __syncthreads();                        // S3: publish wave sums + h_c
        const float inv = fast_rcp(red[4] + red[5] + red[6] + red[7]);
        float wgt[4];
#pragma unroll
        for (int j = 0; j < 4; j++) wgt[j] = pex[j] * inv;
        if (q == 0) {
#pragma unroll
            for (int j = 0; j < 4; j++) W_out[64 * w + 16 * j + m] = wgt[j];
        }

        // ---- MFMA C-path (single fp16) + weighted agg ----
        f32x4_t ap = {0.f, 0.f, 0.f, 0.f};
#pragma unroll
        for (int j = 0; j < 4; j++) {
            const int row = 64 * w + 16 * j + m;
            const uint2_t rc2 = *(const uint2_t*)&hA[row * 10 + 2 * q];
            f32x4_t zz = {0.f, 0.f, 0.f, 0.f};
            const f32x4_t oc = __builtin_amdgcn_mfma_f32_16x16x16f16(
                ACf, __builtin_bit_cast(half4_t, rc2), zz, 0, 0, 0);
#pragma unroll
            for (int i = 0; i < 4; i++)
                ap[i] = fmaf(silu_f(oc[i] + b2cv[i]), wgt[j], ap[i]);
        }
#pragma unroll
        for (int off = 1; off <= 8; off <<= 1) {
            ap[0] += __shfl_xor(ap[0], off, 64);
            ap[1] += __shfl_xor(ap[1], off, 64);
            ap[2] += __shfl_xor(ap[2], off, 64);
            ap[3] += __shfl_xor(ap[3], off, 64);
        }
        if (m == 0)
            *(float4*)&aggw[w][4 * q] = make_float4(ap[0], ap[1], ap[2], ap[3]);
        __syncthreads();                        // S4: publish agg partials; hA free
        if (tid < 16)
            agg_ws[((size_t)b * Tn + t) * 16 + tid] =
                aggw[0][tid] + aggw[1][tid] + aggw[2][tid] + aggw[3][tid];
    }
}

// ---------------- C2: raw = W@V  (LDS-tiled, 64t x 64r x 256k per block) ----------------
__global__ __launch_bounds__(256) void matvec_kernel(
    const float* __restrict__ V, const float* __restrict__ Wg,
    float* __restrict__ out)
{
    const int tb = blockIdx.x, rq = blockIdx.y, b = blockIdx.z;
    const int t0 = tb * 64, r0 = rq * 64;
    const int tid = threadIdx.x;
    __shared__ float4 Wl[64 * 64];   // [tt][k4]  64 KiB
    __shared__ float4 Vl[256 * 16];  // [k][q]    64 KiB

    const float4* Wg4 = (const float4*)Wg;
#pragma unroll
    for (int ch = 0; ch < 16; ch++) {
        const int idx = ch * 256 + tid;
        const int tt = idx >> 6, c4 = idx & 63;
        const int t = t0 + tt;
        Wl[idx] = (t < Tn) ? Wg4[(((size_t)b * Tn + t) * Kn >> 2) + c4]
                           : make_float4(0.f, 0.f, 0.f, 0.f);
    }
    const float4* V4 = (const float4*)V;
#pragma unroll
    for (int ch = 0; ch < 16; ch++) {
        const int idx = ch * 256 + tid;
        const int k = idx >> 4, qq = idx & 15;
        Vl[idx] = V4[(((size_t)b * Kn + k) * Rn >> 2) + (r0 >> 2) + qq];
    }
    __syncthreads();

    const int tg = tid >> 4, rg = tid & 15;
    float4 acc[4];
#pragma unroll
    for (int i = 0; i < 4; i++) acc[i] = make_float4(0.f, 0.f, 0.f, 0.f);

    for (int k4 = 0; k4 < 64; k4++) {
        const float4 v0 = Vl[(k4 * 4 + 0) * 16 + rg];
        const float4 v1 = Vl[(k4 * 4 + 1) * 16 + rg];
        const float4 v2 = Vl[(k4 * 4 + 2) * 16 + rg];
        const float4 v3 = Vl[(k4 * 4 + 3) * 16 + rg];
#pragma unroll
        for (int i = 0; i < 4; i++) {
            const float4 wv = Wl[(tg * 4 + i) * 64 + k4];
            acc[i].x = fmaf(wv.x, v0.x, acc[i].x);
            acc[i].y = fmaf(wv.x, v0.y, acc[i].y);
            acc[i].z = fmaf(wv.x, v0.z, acc[i].z);
            acc[i].w = fmaf(wv.x, v0.w, acc[i].w);
            acc[i].x = fmaf(wv.y, v1.x, acc[i].x);
            acc[i].y = fmaf(wv.y, v1.y, acc[i].y);
            acc[i].z = fmaf(wv.y, v1.z, acc[i].z);
            acc[i].w = fmaf(wv.y, v1.w, acc[i].w);
            acc[i].x = fmaf(wv.z, v2.x, acc[i].x);
            acc[i].y = fmaf(wv.z, v2.y, acc[i].y);
            acc[i].z = fmaf(wv.z, v2.z, acc[i].z);
            acc[i].w = fmaf(wv.z, v2.w, acc[i].w);
            acc[i].x = fmaf(wv.w, v3.x, acc[i].x);
            acc[i].y = fmaf(wv.w, v3.y, acc[i].y);
            acc[i].z = fmaf(wv.w, v3.z, acc[i].z);
            acc[i].w = fmaf(wv.w, v3.w, acc[i].w);
        }
    }

#pragma unroll
    for (int i = 0; i < 4; i++) {
        const int t = t0 + tg * 4 + i;
        if (t < Tn)
            *(float4*)(out + ((size_t)b * Tn + t) * Rn + r0 + rg * 4) = acc[i];
    }
}

// ---------------- C3: wave-per-t finish: up = raw + agg@lin_e + b -> LN ----------------
__global__ __launch_bounds__(256) void ln_kernel(
    const float* __restrict__ agg_ws, const int* __restrict__ len_ws,
    const float* __restrict__ lin_e_w, const float* __restrict__ lin_e_b,
    const float* __restrict__ ln_o_g, const float* __restrict__ ln_o_b,
    float* __restrict__ out)
{
    const int b = blockIdx.y, tid = threadIdx.x;
    const int sub = tid >> 6, lane = tid & 63;
    const int t = blockIdx.x * 4 + sub;
    const int r0 = lane * 4;
    float* __restrict__ row = out + ((size_t)b * Tn + t) * Rn;
    const int len = len_ws[b];
    if (t >= len) {
        *(float4*)(row + r0) = make_float4(0.f, 0.f, 0.f, 0.f);
        return;
    }

    float4 acc = *(const float4*)(row + r0);
    {
        const float4 be = *(const float4*)(lin_e_b + r0);
        acc.x += be.x; acc.y += be.y; acc.z += be.z; acc.w += be.w;
    }
    const float* aggp = agg_ws + ((size_t)b * Tn + t) * 16;
#pragma unroll
    for (int p = 0; p < 16; p++) {
        const float a = aggp[p];
        const float4 l = *(const float4*)(lin_e_w + p * Rn + r0);
        acc.x = fmaf(a, l.x, acc.x); acc.y = fmaf(a, l.y, acc.y);
        acc.z = fmaf(a, l.z, acc.z); acc.w = fmaf(a, l.w, acc.w);
    }

    float s = (acc.x + acc.y) + (acc.z + acc.w);
#pragma unroll
    for (int off = 1; off <= 32; off <<= 1) s += __shfl_xor(s, off, 64);
    const float mu = s * (1.f / Rn);
    const float d0 = acc.x - mu, d1 = acc.y - mu, d2 = acc.z - mu, d3 = acc.w - mu;
    float vr = d0 * d0 + d1 * d1 + d2 * d2 + d3 * d3;
#pragma unroll
    for (int off = 1; off <= 32; off <<= 1) vr += __shfl_xor(vr, off, 64);
    const float rs = rsqrtf(vr * (1.f / Rn) + 1e-5f);

    const float4 g = *(const float4*)(ln_o_g + r0);
    const float4 bb = *(const float4*)(ln_o_b + r0);
    float4 res;
    res.x = d0 * rs * g.x + bb.x;
    res.y = d1 * rs * g.y + bb.y;
    res.z = d2 * rs * g.z + bb.z;
    res.w = d3 * rs * g.w + bb.w;
    *(float4*)(row + r0) = res;
}

// ---------------- launch ----------------
extern "C" void kernel_launch(void* const* d_in, const int* in_sizes, int n_in,
                              void* d_out, int out_size, void* d_ws, size_t ws_size,
                              hipStream_t stream)
{
    const float* dur       = (const float*)d_in[0];
    const float* V         = (const float*)d_in[1];
    const unsigned char* text_mask = (const unsigned char*)d_in[3];
    const float* conv_c_w  = (const float*)d_in[4];
    const float* conv_c_b  = (const float*)d_in[5];
    const float* bn_c_g    = (const float*)d_in[6];
    const float* bn_c_b    = (const float*)d_in[7];
    const float* ln_c_g    = (const float*)d_in[8];
    const float* ln_c_b    = (const float*)d_in[9];
    const float* conv_w_w  = (const float*)d_in[10];
    const float* conv_w_b  = (const float*)d_in[11];
    const float* bn_w_g    = (const float*)d_in[12];
    const float* bn_w_b    = (const float*)d_in[13];
    const float* ln_w_g    = (const float*)d_in[14];
    const float* ln_w_b    = (const float*)d_in[15];
    const float* swc_w1    = (const float*)d_in[16];
    const float* swc_b1    = (const float*)d_in[17];
    const float* swc_w2    = (const float*)d_in[18];
    const float* swc_b2    = (const float*)d_in[19];
    const float* sww_w1    = (const float*)d_in[20];
    const float* sww_b1    = (const float*)d_in[21];
    const float* sww_w2    = (const float*)d_in[22];
    const float* sww_b2    = (const float*)d_in[23];
    const float* proj_w_w  = (const float*)d_in[24];
    const float* proj_w_b  = (const float*)d_in[25];
    const float* lin_e_w   = (const float*)d_in[26];
    const float* lin_e_b   = (const float*)d_in[27];
    const float* ln_o_g    = (const float*)d_in[28];
    const float* ln_o_b    = (const float*)d_in[29];

    float* out = (float*)d_out;
    float* wsf = (float*)d_ws;
    float* s_k    = wsf;                        // 4096
    float* e_k    = wsf + 4096;                 // 4096
    int*   len_ws = (int*)(wsf + 8192);         // 16 (pad 64)
    float* ab_ws  = wsf + 8192 + 64;            // 262144 (alpha/beta per (b,k): 64 floats)
    float* scratch = ab_ws + 262144;            // 524288: part, then aliased as agg_ws
    float* part   = scratch;
    float* agg_ws = scratch;

    scan_kernel<<<dim3(Bn), dim3(Kn), 0, stream>>>(dur, s_k, e_k, len_ws, out);
    conv_partial_kernel<<<dim3(8, Bn), dim3(256), 0, stream>>>(V, conv_w_w, conv_c_w, part);
    conv_finish_kernel<<<dim3(Bn), dim3(256), 0, stream>>>(
        part, text_mask, s_k, e_k,
        conv_w_b, bn_w_g, bn_w_b, ln_w_g, ln_w_b,
        conv_c_b, bn_c_g, bn_c_b, ln_c_g, ln_c_b,
        sww_w1, sww_b1, swc_w1, swc_b1,
        ab_ws);
    logits_kernel<<<dim3(Tn / 2, Bn), dim3(256), 0, stream>>>(
        text_mask, len_ws, ab_ws,
        sww_w2, sww_b2, proj_w_w, proj_w_b,
        swc_w2, swc_b2,
        agg_ws, out);
    matvec_kernel<<<dim3(16, 4, Bn), dim3(256), 0, stream>>>(
        V, out + W_OFF, out);
    ln_kernel<<<dim3(Tn / 4, Bn), dim3(256), 0, stream>>>(
        agg_ws, len_ws, lin_e_w, lin_e_b, ln_o_g, ln_o_b, out);
}

// Round 6
// 178.117 us; speedup vs baseline: 3.8333x; 1.1108x over previous
//
#include <hip/hip_runtime.h>
#include <cstddef>

constexpr int Bn = 16, Kn = 256, Rn = 256, Tn = 1000, C8 = 8, SW = 16;
constexpr size_t UP_SZ    = (size_t)Bn * Tn * Rn;          // 4,096,000
constexpr size_t MASK_OFF = UP_SZ;                          // + 16,000
constexpr size_t LEN_OFF  = MASK_OFF + (size_t)Bn * Tn;     // + 16
constexpr size_t W_OFF    = LEN_OFF + Bn;                    // + 4,096,000

using half4_t = __attribute__((ext_vector_type(4))) _Float16;
using f32x4_t = __attribute__((ext_vector_type(4))) float;
using uint2_t = __attribute__((ext_vector_type(2))) unsigned int;

__device__ __forceinline__ float fast_rcp(float x) { return __builtin_amdgcn_rcpf(x); }
__device__ __forceinline__ float fast_exp2(float x) { return __builtin_amdgcn_exp2f(x); }
constexpr float LOG2E = 1.44269504088896340736f;
__device__ __forceinline__ float silu_f(float x) {
    return x * fast_rcp(1.f + fast_exp2(-LOG2E * x));
}

// ---------------- conv phase A: partial sums over r-chunks ----------------
__global__ __launch_bounds__(256) void conv_partial_kernel(
    const float* __restrict__ V,
    const float* __restrict__ wW, const float* __restrict__ wC,
    float* __restrict__ part)
{
    const int rc = blockIdx.x, b = blockIdx.y, k = threadIdx.x;
    constexpr int RPAD = 33;
    __shared__ float vt[258 * RPAD];
    if (k < 16) {
        const int row = (k < 8) ? 0 : 257;
        const int j = (k & 7) * 4;
        vt[row * RPAD + j] = 0.f; vt[row * RPAD + j + 1] = 0.f;
        vt[row * RPAD + j + 2] = 0.f; vt[row * RPAD + j + 3] = 0.f;
    }
    const float* vsrc = V + ((size_t)(b * Kn + k)) * Rn + rc * 32;
#pragma unroll
    for (int j = 0; j < 8; j++) {
        const float4 qv = *(const float4*)(vsrc + j * 4);
        float* dst = &vt[(k + 1) * RPAD + j * 4];
        dst[0] = qv.x; dst[1] = qv.y; dst[2] = qv.z; dst[3] = qv.w;
    }
    __syncthreads();

    float aw[C8], ac[C8];
#pragma unroll
    for (int c = 0; c < C8; c++) { aw[c] = 0.f; ac[c] = 0.f; }
    for (int dk = 0; dk < 3; dk++) {
        const float* wp = wW + (size_t)(dk * Rn + rc * 32) * C8;
        const float* cp = wC + (size_t)(dk * Rn + rc * 32) * C8;
        const float* vrow = &vt[(k + dk) * RPAD];
#pragma unroll 4
        for (int r = 0; r < 32; r++) {
            const float v = vrow[r];
#pragma unroll
            for (int c = 0; c < C8; c++) {
                aw[c] = fmaf(v, wp[r * C8 + c], aw[c]);
                ac[c] = fmaf(v, cp[r * C8 + c], ac[c]);
            }
        }
    }
    float* dst = part + ((size_t)(b * 8 + rc) * Kn + k) * 16;
    *(float4*)(dst + 0)  = make_float4(aw[0], aw[1], aw[2], aw[3]);
    *(float4*)(dst + 4)  = make_float4(aw[4], aw[5], aw[6], aw[7]);
    *(float4*)(dst + 8)  = make_float4(ac[0], ac[1], ac[2], ac[3]);
    *(float4*)(dst + 12) = make_float4(ac[4], ac[5], ac[6], ac[7]);
}

// ---------------- conv phase B (fused with scan): reduce + post + beta/alpha ----------------
__device__ __forceinline__ void conv_post(
    const float* acc, const float* cb, const float* bng, const float* bnb,
    const float* lng, const float* lnb, const float* w1, const float* b1,
    float* __restrict__ dst)
{
    const float bnscale = rsqrtf(1.f + 1e-5f);
    float x[C8];
    float mu = 0.f;
#pragma unroll
    for (int c = 0; c < C8; c++) {
        float v = (acc[c] + cb[c]) * (bng[c] * bnscale) + bnb[c];
        v = silu_f(v);
        x[c] = v; mu += v;
    }
    mu *= (1.f / C8);
    float var = 0.f;
#pragma unroll
    for (int c = 0; c < C8; c++) { float dd = x[c] - mu; var += dd * dd; }
    var *= (1.f / C8);
    const float rs = rsqrtf(var + 1e-5f);
    float y[C8];
#pragma unroll
    for (int c = 0; c < C8; c++) y[c] = (x[c] - mu) * rs * lng[c] + lnb[c];
#pragma unroll
    for (int c2 = 0; c2 < SW; c2++) {
        float a = b1[c2];
#pragma unroll
        for (int p = 0; p < C8; p++) a = fmaf(y[p], w1[(2 + p) * SW + c2], a);
        dst[c2] = a;
    }
}

__global__ __launch_bounds__(256) void conv_scan_finish_kernel(
    const float* __restrict__ dur,
    const float* __restrict__ part,
    const unsigned char* __restrict__ tmask_g,
    const float* __restrict__ bW, const float* __restrict__ bngW, const float* __restrict__ bnbW,
    const float* __restrict__ lngW, const float* __restrict__ lnbW,
    const float* __restrict__ bC, const float* __restrict__ bngC, const float* __restrict__ bnbC,
    const float* __restrict__ lngC, const float* __restrict__ lnbC,
    const float* __restrict__ sww_w1, const float* __restrict__ sww_b1,
    const float* __restrict__ swc_w1, const float* __restrict__ swc_b1,
    float* __restrict__ alpha_ws, float* __restrict__ ab_ws,
    int* __restrict__ len_ws, float* __restrict__ out)
{
    const int b = blockIdx.x, k = threadIdx.x;
    __shared__ float sc[Kn];
    const float d = dur[b * Kn + k];
    sc[k] = d;
    __syncthreads();
    for (int off = 1; off < Kn; off <<= 1) {
        float v = (k >= off) ? sc[k - off] : 0.f;
        __syncthreads();
        sc[k] += v;
        __syncthreads();
    }
    const float ek = sc[k];
    const float sk = ek - d;
    const float total = sc[Kn - 1];
    int len = (int)rintf(total);
    if (len > Tn) len = Tn;
    if (k == 0) { len_ws[b] = len; out[LEN_OFF + b] = (float)len; }
    for (int t = k; t < Tn; t += 256)
        out[MASK_OFF + (size_t)b * Tn + t] = (t >= len) ? 1.f : 0.f;
    if (b == 0 && k < 16) {
        alpha_ws[k]      = sww_w1[k] - sww_w1[SW + k];
        alpha_ws[16 + k] = swc_w1[k] - swc_w1[SW + k];
    }

    float aw[C8], ac[C8];
#pragma unroll
    for (int c = 0; c < C8; c++) { aw[c] = 0.f; ac[c] = 0.f; }
#pragma unroll 2
    for (int rc = 0; rc < 8; rc++) {
        const float4* p = (const float4*)(part + ((size_t)(b * 8 + rc) * Kn + k) * 16);
        const float4 q0 = p[0], q1 = p[1], q2 = p[2], q3 = p[3];
        aw[0] += q0.x; aw[1] += q0.y; aw[2] += q0.z; aw[3] += q0.w;
        aw[4] += q1.x; aw[5] += q1.y; aw[6] += q1.z; aw[7] += q1.w;
        ac[0] += q2.x; ac[1] += q2.y; ac[2] += q2.z; ac[3] += q2.w;
        ac[4] += q3.x; ac[5] += q3.y; ac[6] += q3.z; ac[7] += q3.w;
    }
    float basew[SW], basec[SW];
    conv_post(aw, bW, bngW, bnbW, lngW, lnbW, sww_w1, sww_b1, basew);
    conv_post(ac, bC, bngC, bnbC, lngC, lnbC, swc_w1, swc_b1, basec);

    const bool msk = tmask_g[b * Kn + k] != 0;
    float* dst = ab_ws + ((size_t)(b * Kn) + k) * 32;
#pragma unroll
    for (int c = 0; c < SW; c++) {
        const float w0w = sww_w1[c], w1w_ = sww_w1[SW + c];
        const float w0c = swc_w1[c], w1c_ = swc_w1[SW + c];
        dst[c]      = msk ? basew[c] : fmaf(ek, w1w_, fmaf(-sk, w0w, basew[c]));
        dst[16 + c] = msk ? basec[c] : fmaf(ek, w1c_, fmaf(-sk, w0c, basec[c]));
    }
}

// ---------------- C1: swish blocks via MFMA + softmax + W + agg (4 t/block) ----------------
__global__ __launch_bounds__(256) void logits_kernel(
    const unsigned char* __restrict__ tm, const int* __restrict__ len_ws,
    const float* __restrict__ alpha_ws, const float* __restrict__ ab_ws,
    const float* __restrict__ sww_w2, const float* __restrict__ sww_b2,
    const float* __restrict__ proj_w, const float* __restrict__ proj_b,
    const float* __restrict__ swc_w2, const float* __restrict__ swc_b2,
    float* __restrict__ agg_ws, float* __restrict__ out)
{
    const int t0 = blockIdx.x * 4, b = blockIdx.y, tid = threadIdx.x;
    const int lane = tid & 63, w = tid >> 6, q = lane >> 4, m = lane & 15;
    const int len = len_ws[b];

    __shared__ __align__(16) unsigned int hA[256 * 10];  // h_w hi
    __shared__ __align__(16) unsigned int hB[256 * 10];  // h_w lo
    __shared__ __align__(16) unsigned int hC[256 * 10];  // h_c
    __shared__ float red[8];
    __shared__ __align__(16) float aggw[2][4][16];

    // per-thread beta vectors (alpha is uniform -> SGPRs via alpha_ws[const])
    float bw[16], bc[16];
    {
        const float4* bp = (const float4*)(ab_ws + (((size_t)b * Kn) + tid) * 32);
#pragma unroll
        for (int i = 0; i < 4; i++) {
            const float4 v = bp[i];
            bw[4*i] = v.x; bw[4*i+1] = v.y; bw[4*i+2] = v.z; bw[4*i+3] = v.w;
        }
#pragma unroll
        for (int i = 0; i < 4; i++) {
            const float4 v = bp[4 + i];
            bc[4*i] = v.x; bc[4*i+1] = v.y; bc[4*i+2] = v.z; bc[4*i+3] = v.w;
        }
    }
    const float mk = (tm[b * Kn + tid] != 0) ? 0.f : 1.f;

    // A-fragments (identical pattern to verified r5 kernel)
    half4_t AWhi, AWlo, ACf;
    float pj[4], b2wv[4], b2cv[4], mb[4];
#pragma unroll
    for (int i = 0; i < 4; i++) {
        const int c = 4 * q + i;
        const float vw = sww_w2[c * SW + m];
        const _Float16 hi = (_Float16)vw;
        AWhi[i] = hi;
        AWlo[i] = (_Float16)(vw - (float)hi);
        ACf[i]  = (_Float16)(swc_w2[c * SW + m]);
        pj[i]   = proj_w[c];
        b2wv[i] = sww_b2[c];
        b2cv[i] = swc_b2[c];
        mb[i]   = (tm[b * Kn + 64 * w + 16 * i + m] != 0) ? -INFINITY : 0.f;
    }
    const float pb = proj_b[0];

    int pend = -1, pendpar = 0;

    for (int ti = 0; ti < 4; ti++) {
        const int t = t0 + ti;
        float* __restrict__ W_out = out + W_OFF + ((size_t)b * Tn + t) * Kn;
        if (t >= len) { W_out[tid] = 0.f; continue; }   // uniform over block
        const float u = (float)(t + 1);
        const float umk = u * mk;

        // ---- layer-1: arg = umk*alpha[c] + beta[k][c]; silu; fp16 pack ----
#pragma unroll
        for (int p = 0; p < 8; p++) {
            const float x0 = fmaf(umk, alpha_ws[2*p],   bw[2*p]);
            const float x1 = fmaf(umk, alpha_ws[2*p+1], bw[2*p+1]);
            const float h0 = silu_f(x0), h1 = silu_f(x1);
            const auto hp = __builtin_amdgcn_cvt_pkrtz(h0, h1);
            hA[tid * 10 + p] = __builtin_bit_cast(unsigned int, hp);
            const float l0 = h0 - (float)hp.x, l1 = h1 - (float)hp.y;
            hB[tid * 10 + p] = __builtin_bit_cast(unsigned int,
                                __builtin_amdgcn_cvt_pkrtz(l0, l1));
            const float y0 = fmaf(umk, alpha_ws[16 + 2*p],   bc[2*p]);
            const float y1 = fmaf(umk, alpha_ws[16 + 2*p+1], bc[2*p+1]);
            hC[tid * 10 + p] = __builtin_bit_cast(unsigned int,
                                __builtin_amdgcn_cvt_pkrtz(silu_f(y0), silu_f(y1)));
        }
        // wave-local rows: in-wave DS ordering suffices (no barrier needed)

        // ---- MFMA W-path: split-fp16, 3 mfma per 16x16 tile ----
        f32x4_t o[4];
#pragma unroll
        for (int j = 0; j < 4; j++) {
            const int row = 64 * w + 16 * j + m;
            const uint2_t rh = *(const uint2_t*)&hA[row * 10 + 2 * q];
            const uint2_t rl = *(const uint2_t*)&hB[row * 10 + 2 * q];
            const half4_t bh = __builtin_bit_cast(half4_t, rh);
            const half4_t bl = __builtin_bit_cast(half4_t, rl);
            f32x4_t acc = {0.f, 0.f, 0.f, 0.f};
            acc = __builtin_amdgcn_mfma_f32_16x16x16f16(AWlo, bh, acc, 0, 0, 0);
            acc = __builtin_amdgcn_mfma_f32_16x16x16f16(AWhi, bl, acc, 0, 0, 0);
            acc = __builtin_amdgcn_mfma_f32_16x16x16f16(AWhi, bh, acc, 0, 0, 0);
            o[j] = acc;
        }

        // ---- logit: silu(o + b2) . proj, reduce over c2 ----
        float lg[4];
#pragma unroll
        for (int j = 0; j < 4; j++) {
            float s = silu_f(o[j][0] + b2wv[0]) * pj[0];
            s = fmaf(silu_f(o[j][1] + b2wv[1]), pj[1], s);
            s = fmaf(silu_f(o[j][2] + b2wv[2]), pj[2], s);
            s = fmaf(silu_f(o[j][3] + b2wv[3]), pj[3], s);
            s += __shfl_xor(s, 16, 64);
            s += __shfl_xor(s, 32, 64);
            lg[j] = s + pb + mb[j];
        }

        // ---- softmax over 256 rows ----
        float mx = fmaxf(fmaxf(lg[0], lg[1]), fmaxf(lg[2], lg[3]));
#pragma unroll
        for (int off = 1; off <= 8; off <<= 1) mx = fmaxf(mx, __shfl_xor(mx, off, 64));
        if (lane == 0) red[w] = mx;
        __syncthreads();                        // S2: publish wave maxima
        if (pend >= 0) {                        // deferred agg finalize for t-1
            if (tid < 16)
                agg_ws[((size_t)b * Tn + pend) * 16 + tid] =
                    aggw[pendpar][0][tid] + aggw[pendpar][1][tid] +
                    aggw[pendpar][2][tid] + aggw[pendpar][3][tid];
            pend = -1;
        }
        const float M = fmaxf(fmaxf(red[0], red[1]), fmaxf(red[2], red[3]));
        float pex[4];
#pragma unroll
        for (int j = 0; j < 4; j++) pex[j] = fast_exp2(LOG2E * (lg[j] - M));
        float ssum = (pex[0] + pex[1]) + (pex[2] + pex[3]);
#pragma unroll
        for (int off = 1; off <= 8; off <<= 1) ssum += __shfl_xor(ssum, off, 64);
        if (lane == 0) red[4 + w] = ssum;
        __syncthreads();                        // S3: publish wave sums
        const float inv = fast_rcp(red[4] + red[5] + red[6] + red[7]);
        float wgt[4];
#pragma unroll
        for (int j = 0; j < 4; j++) wgt[j] = pex[j] * inv;
        if (q == 0) {
#pragma unroll
            for (int j = 0; j < 4; j++) W_out[64 * w + 16 * j + m] = wgt[j];
        }

        // ---- MFMA C-path (single fp16 from hC) + weighted agg ----
        f32x4_t ap = {0.f, 0.f, 0.f, 0.f};
#pragma unroll
        for (int j = 0; j < 4; j++) {
            const int row = 64 * w + 16 * j + m;
            const uint2_t rc2 = *(const uint2_t*)&hC[row * 10 + 2 * q];
            f32x4_t zz = {0.f, 0.f, 0.f, 0.f};
            const f32x4_t oc = __builtin_amdgcn_mfma_f32_16x16x16f16(
                ACf, __builtin_bit_cast(half4_t, rc2), zz, 0, 0, 0);
#pragma unroll
            for (int i = 0; i < 4; i++)
                ap[i] = fmaf(silu_f(oc[i] + b2cv[i]), wgt[j], ap[i]);
        }
#pragma unroll
        for (int off = 1; off <= 8; off <<= 1) {
            ap[0] += __shfl_xor(ap[0], off, 64);
            ap[1] += __shfl_xor(ap[1], off, 64);
            ap[2] += __shfl_xor(ap[2], off, 64);
            ap[3] += __shfl_xor(ap[3], off, 64);
        }
        if (m == 0)
            *(float4*)&aggw[ti & 1][w][4 * q] = make_float4(ap[0], ap[1], ap[2], ap[3]);
        pend = t; pendpar = ti & 1;
    }
    if (pend >= 0) {
        __syncthreads();
        if (tid < 16)
            agg_ws[((size_t)b * Tn + pend) * 16 + tid] =
                aggw[pendpar][0][tid] + aggw[pendpar][1][tid] +
                aggw[pendpar][2][tid] + aggw[pendpar][3][tid];
    }
}

// ---------------- C2: raw = W@V, 64t x 64r, K split in 2 stages (64 KiB LDS) ----------------
__global__ __launch_bounds__(256) void matvec_kernel(
    const float* __restrict__ V, const float* __restrict__ Wg,
    float* __restrict__ out)
{
    const int tb = blockIdx.x, rq = blockIdx.y, b = blockIdx.z;
    const int t0 = tb * 64, r0 = rq * 64;
    const int tid = threadIdx.x;
    __shared__ float4 Wl[64 * 32];   // [tt][k4-half]  32 KiB
    __shared__ float4 Vl[128 * 16];  // [k-half][q]    32 KiB

    const int tg = tid >> 4, rg = tid & 15;
    float4 acc[4];
#pragma unroll
    for (int i = 0; i < 4; i++) acc[i] = make_float4(0.f, 0.f, 0.f, 0.f);

    const float4* Wg4 = (const float4*)Wg;
    const float4* V4 = (const float4*)V;

    for (int kh = 0; kh < 2; kh++) {
        __syncthreads();    // kh=1: previous compute must finish reading
#pragma unroll
        for (int ch = 0; ch < 8; ch++) {
            const int idx = ch * 256 + tid;          // 0..2047
            const int tt = idx >> 5, c4 = idx & 31;
            const int t = t0 + tt;
            Wl[idx] = (t < Tn) ? Wg4[(((size_t)b * Tn + t) * Kn >> 2) + kh * 32 + c4]
                               : make_float4(0.f, 0.f, 0.f, 0.f);
        }
#pragma unroll
        for (int ch = 0; ch < 8; ch++) {
            const int idx = ch * 256 + tid;
            const int k = idx >> 4, qq = idx & 15;
            Vl[idx] = V4[(((size_t)b * Kn + kh * 128 + k) * Rn >> 2) + (r0 >> 2) + qq];
        }
        __syncthreads();

        for (int k4 = 0; k4 < 32; k4++) {
            const float4 v0 = Vl[(k4 * 4 + 0) * 16 + rg];
            const float4 v1 = Vl[(k4 * 4 + 1) * 16 + rg];
            const float4 v2 = Vl[(k4 * 4 + 2) * 16 + rg];
            const float4 v3 = Vl[(k4 * 4 + 3) * 16 + rg];
#pragma unroll
            for (int i = 0; i < 4; i++) {
                const float4 wv = Wl[(tg * 4 + i) * 32 + k4];
                acc[i].x = fmaf(wv.x, v0.x, acc[i].x);
                acc[i].y = fmaf(wv.x, v0.y, acc[i].y);
                acc[i].z = fmaf(wv.x, v0.z, acc[i].z);
                acc[i].w = fmaf(wv.x, v0.w, acc[i].w);
                acc[i].x = fmaf(wv.y, v1.x, acc[i].x);
                acc[i].y = fmaf(wv.y, v1.y, acc[i].y);
                acc[i].z = fmaf(wv.y, v1.z, acc[i].z);
                acc[i].w = fmaf(wv.y, v1.w, acc[i].w);
                acc[i].x = fmaf(wv.z, v2.x, acc[i].x);
                acc[i].y = fmaf(wv.z, v2.y, acc[i].y);
                acc[i].z = fmaf(wv.z, v2.z, acc[i].z);
                acc[i].w = fmaf(wv.z, v2.w, acc[i].w);
                acc[i].x = fmaf(wv.w, v3.x, acc[i].x);
                acc[i].y = fmaf(wv.w, v3.y, acc[i].y);
                acc[i].z = fmaf(wv.w, v3.z, acc[i].z);
                acc[i].w = fmaf(wv.w, v3.w, acc[i].w);
            }
        }
    }

#pragma unroll
    for (int i = 0; i < 4; i++) {
        const int t = t0 + tg * 4 + i;
        if (t < Tn)
            *(float4*)(out + ((size_t)b * Tn + t) * Rn + r0 + rg * 4) = acc[i];
    }
}

// ---------------- C3: wave-per-t finish: up = raw + agg@lin_e + b -> LN ----------------
__global__ __launch_bounds__(256) void ln_kernel(
    const float* __restrict__ agg_ws, const int* __restrict__ len_ws,
    const float* __restrict__ lin_e_w, const float* __restrict__ lin_e_b,
    const float* __restrict__ ln_o_g, const float* __restrict__ ln_o_b,
    float* __restrict__ out)
{
    const int b = blockIdx.y, tid = threadIdx.x;
    const int sub = tid >> 6, lane = tid & 63;
    const int t = blockIdx.x * 4 + sub;
    const int r0 = lane * 4;
    float* __restrict__ row = out + ((size_t)b * Tn + t) * Rn;
    const int len = len_ws[b];
    if (t >= len) {
        *(float4*)(row + r0) = make_float4(0.f, 0.f, 0.f, 0.f);
        return;
    }

    float4 acc = *(const float4*)(row + r0);
    {
        const float4 be = *(const float4*)(lin_e_b + r0);
        acc.x += be.x; acc.y += be.y; acc.z += be.z; acc.w += be.w;
    }
    const float* aggp = agg_ws + ((size_t)b * Tn + t) * 16;
#pragma unroll
    for (int p = 0; p < 16; p++) {
        const float a = aggp[p];
        const float4 l = *(const float4*)(lin_e_w + p * Rn + r0);
        acc.x = fmaf(a, l.x, acc.x); acc.y = fmaf(a, l.y, acc.y);
        acc.z = fmaf(a, l.z, acc.z); acc.w = fmaf(a, l.w, acc.w);
    }

    float s = (acc.x + acc.y) + (acc.z + acc.w);
#pragma unroll
    for (int off = 1; off <= 32; off <<= 1) s += __shfl_xor(s, off, 64);
    const float mu = s * (1.f / Rn);
    const float d0 = acc.x - mu, d1 = acc.y - mu, d2 = acc.z - mu, d3 = acc.w - mu;
    float vr = d0 * d0 + d1 * d1 + d2 * d2 + d3 * d3;
#pragma unroll
    for (int off = 1; off <= 32; off <<= 1) vr += __shfl_xor(vr, off, 64);
    const float rs = rsqrtf(vr * (1.f / Rn) + 1e-5f);

    const float4 g = *(const float4*)(ln_o_g + r0);
    const float4 bb = *(const float4*)(ln_o_b + r0);
    float4 res;
    res.x = d0 * rs * g.x + bb.x;
    res.y = d1 * rs * g.y + bb.y;
    res.z = d2 * rs * g.z + bb.z;
    res.w = d3 * rs * g.w + bb.w;
    *(float4*)(row + r0) = res;
}

// ---------------- launch ----------------
extern "C" void kernel_launch(void* const* d_in, const int* in_sizes, int n_in,
                              void* d_out, int out_size, void* d_ws, size_t ws_size,
                              hipStream_t stream)
{
    const float* dur       = (const float*)d_in[0];
    const float* V         = (const float*)d_in[1];
    const unsigned char* text_mask = (const unsigned char*)d_in[3];
    const float* conv_c_w  = (const float*)d_in[4];
    const float* conv_c_b  = (const float*)d_in[5];
    const float* bn_c_g    = (const float*)d_in[6];
    const float* bn_c_b    = (const float*)d_in[7];
    const float* ln_c_g    = (const float*)d_in[8];
    const float* ln_c_b    = (const float*)d_in[9];
    const float* conv_w_w  = (const float*)d_in[10];
    const float* conv_w_b  = (const float*)d_in[11];
    const float* bn_w_g    = (const float*)d_in[12];
    const float* bn_w_b    = (const float*)d_in[13];
    const float* ln_w_g    = (const float*)d_in[14];
    const float* ln_w_b    = (const float*)d_in[15];
    const float* swc_w1    = (const float*)d_in[16];
    const float* swc_b1    = (const float*)d_in[17];
    const float* swc_w2    = (const float*)d_in[18];
    const float* swc_b2    = (const float*)d_in[19];
    const float* sww_w1    = (const float*)d_in[20];
    const float* sww_b1    = (const float*)d_in[21];
    const float* sww_w2    = (const float*)d_in[22];
    const float* sww_b2    = (const float*)d_in[23];
    const float* proj_w_w  = (const float*)d_in[24];
    const float* proj_w_b  = (const float*)d_in[25];
    const float* lin_e_w   = (const float*)d_in[26];
    const float* lin_e_b   = (const float*)d_in[27];
    const float* ln_o_g    = (const float*)d_in[28];
    const float* ln_o_b    = (const float*)d_in[29];

    float* out = (float*)d_out;
    float* wsf = (float*)d_ws;
    int*   len_ws   = (int*)wsf;                // 16 (pad 64)
    float* alpha_ws = wsf + 64;                 // 32 (pad 64)
    float* ab_ws    = wsf + 128;                // 16*256*32 = 131072
    float* scratch  = ab_ws + 131072;           // part 524288, then aliased agg 256000
    float* part     = scratch;
    float* agg_ws   = scratch;

    conv_partial_kernel<<<dim3(8, Bn), dim3(256), 0, stream>>>(V, conv_w_w, conv_c_w, part);
    conv_scan_finish_kernel<<<dim3(Bn), dim3(256), 0, stream>>>(
        dur, part, text_mask,
        conv_w_b, bn_w_g, bn_w_b, ln_w_g, ln_w_b,
        conv_c_b, bn_c_g, bn_c_b, ln_c_g, ln_c_b,
        sww_w1, sww_b1, swc_w1, swc_b1,
        alpha_ws, ab_ws, len_ws, out);
    logits_kernel<<<dim3(Tn / 4, Bn), dim3(256), 0, stream>>>(
        text_mask, len_ws, alpha_ws, ab_ws,
        sww_w2, sww_b2, proj_w_w, proj_w_b,
        swc_w2, swc_b2,
        agg_ws, out);
    matvec_kernel<<<dim3(16, 4, Bn), dim3(256), 0, stream>>>(
        V, out + W_OFF, out);
    ln_kernel<<<dim3(Tn / 4, Bn), dim3(256), 0, stream>>>(
        agg_ws, len_ws, lin_e_w, lin_e_b, ln_o_g, ln_o_b, out);
}